// Round 18
// baseline (367.009 us; speedup 1.0000x reference)
//
#include <hip/hip_runtime.h>
#include <hip/hip_bf16.h>
#include <cmath>

// ---------------------------------------------------------------------------
// Pipeline: y1 = bn_relu(dcn(x, w_off1, b_off1, w1, b1))        (4,128,64,64)
//           up = up_depthwise(y1, w_up, f=2)                    (4,128,128,128)
//           out = bn_relu(dcn(up, w_off2, b_off2, w2, b2))      (4,128,128,128)
// ALL GEMM-shaped work on mfma_f32_16x16x32_bf16, split-bf16 (hi/lo, 3 prod).
// R18: dcn2 S DOUBLE-buffer + ONE barrier/chunk — MFMA(S[cur]) overlaps
//      finish->S[cur^1] and issue(ch+2) within the same phase (MFMA pipe ||
//      VALU pipe || gathers in flight). Barriers 72 -> 37 per block.
// R17: A-JIT (no A LDS stage; frag-order, L2-resident). R14: M-split waves.
// pack via v_cvt_pk_bf16_f32; s_setprio on MFMA clusters.
// conv_off -> conv_mfma (M=27 padded to 32, tap-sampler B).
// Workspace: om1 | y1 | up | om2 ; w1+wo1 splits parked in `up`,
// w2+wo2 splits parked in `y1`.
// ---------------------------------------------------------------------------

#define EPSV 1e-5f

typedef __attribute__((ext_vector_type(8))) short short8;
typedef __attribute__((ext_vector_type(4))) float f32x4;

__device__ __forceinline__ ushort f2bf(float f) {
    union { float f; uint u; } v; v.f = f;
    const uint r = v.u + 0x7fffu + ((v.u >> 16) & 1u);   // RNE
    return (ushort)(r >> 16);
}
__device__ __forceinline__ float bf2f(ushort h) {
    union { uint u; float f; } v; v.u = ((uint)h) << 16;
    return v.f;
}
__device__ __forceinline__ float2 ld2u(const float* p) {
    float2 v; __builtin_memcpy(&v, p, sizeof(float2)); return v;
}
// packed bf16 RNE convert: dst.lo = bf16(a), dst.hi = bf16(b)
__device__ __forceinline__ uint cvtpk_bf16(float a, float b) {
    uint r;
    asm("v_cvt_pk_bf16_f32 %0, %1, %2" : "=v"(r) : "v"(a), "v"(b));
    return r;
}

// ---- pack 8 fp32 -> bf16 hi/lo rows of S (cvt_pk fast path) ----------------
template <int KS>
__device__ __forceinline__ void pack_store8(
    const float* s, ushort* __restrict__ Shi, ushort* __restrict__ Slo,
    int pp, int j0)
{
    uint hw[4], lw[4];
#pragma unroll
    for (int q = 0; q < 4; ++q) {
        const float s0 = s[2 * q], s1 = s[2 * q + 1];
        const uint h = cvtpk_bf16(s0, s1);
        union { uint u; float f; } h0, h1;
        h0.u = h << 16;
        h1.u = h & 0xffff0000u;
        hw[q] = h;
        lw[q] = cvtpk_bf16(s0 - h0.f, s1 - h1.f);
    }
    uint4 hv; hv.x = hw[0]; hv.y = hw[1]; hv.z = hw[2]; hv.w = hw[3];
    uint4 lv; lv.x = lw[0]; lv.y = lw[1]; lv.z = lw[2]; lv.w = lw[3];
    *(uint4*)&Shi[pp * KS + j0] = hv;
    *(uint4*)&Slo[pp * KS + j0] = lv;
}

// ------- weight split: fp32 -> bf16 hi/lo in per-chunk FRAGMENT order -------
__global__ __launch_bounds__(256) void wsplit_perm_kernel(
    const float* __restrict__ w, ushort* __restrict__ hi,
    ushort* __restrict__ lo, int cin, int n)
{
    const int i = blockIdx.x * 256 + threadIdx.x;
    if (i >= n) return;
    const int cin9 = cin * 9;
    const int co = i / cin9;
    const int k  = i - co * cin9;            // channel-major K index
    const int ch = k >> 5;
    const int kq = (k & 31) >> 3;
    const int j  = k & 7;
    const int mt = co >> 4;
    const int lane = (co & 15) | (kq << 4);
    const size_t dst = ((size_t)(ch * 8 + mt) * 64 + lane) * 8 + j;
    const float f = w[i];
    const ushort h = f2bf(f);
    hi[dst] = h;
    lo[dst] = f2bf(f - bf2f(h));
}

// ------- conv weight split: (27,CIN,3,3) -> M=32 zero-padded frag order -----
__global__ __launch_bounds__(256) void wsplit_perm_conv_kernel(
    const float* __restrict__ w, ushort* __restrict__ hi,
    ushort* __restrict__ lo, int cin, int n)   // n = 32*cin*9
{
    const int i = blockIdx.x * 256 + threadIdx.x;
    if (i >= n) return;
    const int cin9 = cin * 9;
    const int co = i / cin9;
    const int k  = i - co * cin9;
    const int ch = k >> 5;
    const int kq = (k & 31) >> 3;
    const int j  = k & 7;
    const int mt = co >> 4;
    const int lane = (co & 15) | (kq << 4);
    const size_t dst = ((size_t)(ch * 2 + mt) * 64 + lane) * 8 + j;
    const float f = (co < 27) ? w[(size_t)co * cin9 + k] : 0.f;
    const ushort h = f2bf(f);
    hi[dst] = h;
    lo[dst] = f2bf(f - bf2f(h));
}

// ---------------- offset conv on MFMA: 3x3, pad 1, 27(->32) outputs ---------
template <int CIN, int HH, int WW, int POS, int KS>
__device__ __forceinline__ void conv_sample_chunk(
    const float* __restrict__ xb, const uint* __restrict__ toff,
    const float* __restrict__ twt, ushort* __restrict__ Shi,
    ushort* __restrict__ Slo, int tt, int kbase)
{
    constexpr int HW = HH * WW;
    const int pp = tt & (POS - 1);
    const int j0 = (tt / POS) * 8;
    float s[8];
#pragma unroll
    for (int j = 0; j < 8; ++j) {
        const int kg = kbase + j0 + j;
        const int c  = (kg * 7282) >> 16;       // /9 (exact for kg<2304)
        const int k9 = kg - c * 9;
        const int ei = k9 * POS + pp;
        s[j] = xb[(size_t)c * HW + toff[ei]] * twt[ei];
    }
    pack_store8<KS>(s, Shi, Slo, pp, j0);
}

template <int CIN, int HH, int WW, int POS, int KWAVES, int MINW>
__global__ __launch_bounds__((POS / 16) * KWAVES * 64, MINW) void conv_mfma_kernel(
    const float* __restrict__ in,    // (B, CIN, HH, WW)
    const ushort* __restrict__ whi,  // (32, CIN*9) frag order, zero-padded
    const ushort* __restrict__ wlo,
    const float* __restrict__ bias,  // (27)
    float* __restrict__ om)          // (B, 27, HH*WW)
{
    constexpr int HW   = HH * WW;
    constexpr int K    = CIN * 9;
    constexpr int NPQ  = POS / 16;
    constexpr int NT   = NPQ * KWAVES * 64;
    constexpr int KC   = 32;
    constexpr int KS   = 40;
    constexpr int NCHT = K / KC;
    constexpr int NCH  = NCHT / KWAVES;
    constexpr int SBUF = POS * KS;

    extern __shared__ __align__(16) char smem[];
    uint*   toff  = (uint*)smem;              // 9*POS
    float*  twt   = (float*)(toff + 9 * POS); // 9*POS
    ushort* Sbase = (ushort*)(twt + 9 * POS);

    const int tid = threadIdx.x;
    const int nt  = HW / POS;
    const int cpx = gridDim.x >> 3;
    const int bid = (blockIdx.x & 7) * cpx + (blockIdx.x >> 3);
    const int b   = bid / nt;
    const int p0  = (bid - b * nt) * POS;

    for (int i = tid; i < 9 * POS; i += NT) {
        const int k9 = i / POS, pp = i - k9 * POS;
        const int p  = p0 + pp;
        const int yy = p / WW, xx = p - yy * WW;
        const int ky = (k9 * 11) >> 5, kx = k9 - ky * 3;
        const int iy = yy + ky - 1, ix = xx + kx - 1;
        const bool v = (iy >= 0) && (iy < HH) && (ix >= 0) && (ix < WW);
        const int cy = min(max(iy, 0), HH - 1);
        const int cx = min(max(ix, 0), WW - 1);
        toff[i] = (uint)(cy * WW + cx);
        twt[i]  = v ? 1.f : 0.f;
    }
    __syncthreads();

    const float* xb = in + (size_t)b * CIN * HW;
    const int lane = tid & 63;
    const int w    = tid >> 6;
    const int wq   = w & (NPQ - 1);
    const int kgid = w / NPQ;
    const int tt   = tid & (NPQ * 64 - 1);
    ushort* S00 = Sbase + kgid * (4 * SBUF);

    f32x4 acc[2];
    acc[0] = (f32x4){0.f, 0.f, 0.f, 0.f};
    acc[1] = (f32x4){0.f, 0.f, 0.f, 0.f};
    const int mrow = lane & 15;
    const int kq   = lane >> 4;

    conv_sample_chunk<CIN, HH, WW, POS, KS>(xb, toff, twt, S00, S00 + SBUF,
                                            tt, kgid * NCH * KC);
    __syncthreads();

    for (int ch = 0; ch < NCH; ++ch) {
        const int cur = ch & 1;
        ushort* Sc = S00 + (cur * 2) * SBUF;
        const int boff = (wq * 16 + mrow) * KS + kq * 8;
        const short8 bh = *(const short8*)&Sc[boff];
        const short8 bl = *(const short8*)&Sc[SBUF + boff];
        if (ch + 1 < NCH) {
            ushort* Sn = S00 + ((cur ^ 1) * 2) * SBUF;
            conv_sample_chunk<CIN, HH, WW, POS, KS>(xb, toff, twt,
                                                    Sn, Sn + SBUF, tt,
                                                    (kgid * NCH + ch + 1) * KC);
        }
        const size_t abase = (size_t)((kgid * NCH + ch) * 2) * 512;
        __builtin_amdgcn_s_setprio(1);
#pragma unroll
        for (int mt = 0; mt < 2; ++mt) {
            const size_t ao = abase + (size_t)((mt * 64 + lane) * 8);
            const short8 ah = *(const short8*)(whi + ao);
            const short8 al = *(const short8*)(wlo + ao);
            acc[mt] = __builtin_amdgcn_mfma_f32_16x16x32_bf16(al, bh, acc[mt], 0, 0, 0);
            acc[mt] = __builtin_amdgcn_mfma_f32_16x16x32_bf16(ah, bl, acc[mt], 0, 0, 0);
            acc[mt] = __builtin_amdgcn_mfma_f32_16x16x32_bf16(ah, bh, acc[mt], 0, 0, 0);
        }
        __builtin_amdgcn_s_setprio(0);
        __syncthreads();
    }

    const int pcolb = wq * 16 + mrow;
    constexpr int RS = POS + 1;
    constexpr int SL = 32 * RS;
    float* red = (float*)Sbase;

    if constexpr (KWAVES == 4) {
        if (kgid >= 2) {
#pragma unroll
            for (int mt = 0; mt < 2; ++mt)
#pragma unroll
                for (int r = 0; r < 4; ++r) {
                    const int co = mt * 16 + kq * 4 + r;
                    red[(kgid - 2) * SL + co * RS + pcolb] = acc[mt][r];
                }
        }
        __syncthreads();
        if (kgid < 2) {
#pragma unroll
            for (int mt = 0; mt < 2; ++mt)
#pragma unroll
                for (int r = 0; r < 4; ++r) {
                    const int co = mt * 16 + kq * 4 + r;
                    acc[mt][r] += red[kgid * SL + co * RS + pcolb];
                }
        }
        __syncthreads();
        if (kgid == 1) {
#pragma unroll
            for (int mt = 0; mt < 2; ++mt)
#pragma unroll
                for (int r = 0; r < 4; ++r) {
                    const int co = mt * 16 + kq * 4 + r;
                    red[co * RS + pcolb] = acc[mt][r];
                }
        }
        __syncthreads();
        if (kgid == 0) {
#pragma unroll
            for (int mt = 0; mt < 2; ++mt)
#pragma unroll
                for (int r = 0; r < 4; ++r) {
                    const int co = mt * 16 + kq * 4 + r;
                    acc[mt][r] += red[co * RS + pcolb];
                }
        }
    } else if constexpr (KWAVES == 2) {
        if (kgid == 1) {
#pragma unroll
            for (int mt = 0; mt < 2; ++mt)
#pragma unroll
                for (int r = 0; r < 4; ++r) {
                    const int co = mt * 16 + kq * 4 + r;
                    red[co * RS + pcolb] = acc[mt][r];
                }
        }
        __syncthreads();
        if (kgid == 0) {
#pragma unroll
            for (int mt = 0; mt < 2; ++mt)
#pragma unroll
                for (int r = 0; r < 4; ++r) {
                    const int co = mt * 16 + kq * 4 + r;
                    acc[mt][r] += red[co * RS + pcolb];
                }
        }
    }

    if (kgid == 0) {
        float* ob = om + (size_t)b * 27 * HW + p0 + pcolb;
#pragma unroll
        for (int mt = 0; mt < 2; ++mt)
#pragma unroll
            for (int r = 0; r < 4; ++r) {
                const int co = mt * 16 + kq * 4 + r;
                if (co < 27)
                    ob[(size_t)co * HW] = acc[mt][r] + bias[co];
            }
    }
}

// ---------------- paired sampler: issue / finish ----------------------------
template <int CIN, int HH, int WW, int POS>
__device__ __forceinline__ void sample_issue(
    const float* __restrict__ xb, const uint* __restrict__ eoff2,
    float2* v0, float2* v1, int tt, int kbase)
{
    constexpr int HW = HH * WW;
    const int pp = tt & (POS - 1);
    const int j0 = (tt / POS) * 8;
#pragma unroll
    for (int j = 0; j < 8; ++j) {
        const int kg = kbase + j0 + j;
        const int c  = (kg * 7282) >> 16;       // /9 (exact for kg<2304)
        const int k9 = kg - c * 9;
        const uint e = eoff2[k9 * POS + pp];
        const float* chp = xb + (size_t)c * HW;
        v0[j] = ld2u(chp + (e & 0xffffu));
        v1[j] = ld2u(chp + (e >> 16));
    }
}

template <int CIN, int HH, int WW, int POS, int KS>
__device__ __forceinline__ void sample_finish(
    const float4* __restrict__ ewt, const float2* v0, const float2* v1,
    ushort* __restrict__ Shi, ushort* __restrict__ Slo, int tt, int kbase)
{
    const int pp = tt & (POS - 1);
    const int j0 = (tt / POS) * 8;
    float s[8];
#pragma unroll
    for (int j = 0; j < 8; ++j) {
        const int kg = kbase + j0 + j;
        const int c  = (kg * 7282) >> 16;
        const int k9 = kg - c * 9;
        const float4 wv = ewt[k9 * POS + pp];
        s[j] = v0[j].x * wv.x + v0[j].y * wv.y
             + v1[j].x * wv.z + v1[j].y * wv.w;
    }
    pack_store8<KS>(s, Shi, Slo, pp, j0);
}

template <int CIN, int HH, int WW, int POS, int KS>
__device__ __forceinline__ void sample_chunk(
    const float* __restrict__ xb, const uint* __restrict__ eoff2,
    const float4* __restrict__ ewt, ushort* __restrict__ Shi,
    ushort* __restrict__ Slo, int tt, int kbase)
{
    float2 v0[8], v1[8];
    sample_issue<CIN, HH, WW, POS>(xb, eoff2, v0, v1, tt, kbase);
    sample_finish<CIN, HH, WW, POS, KS>(ewt, v0, v1, Shi, Slo, tt, kbase);
}

// ---------------- fused DCN on MFMA: sample + GEMM + bias + BN + ReLU -------
// M-SPLIT: wave wm owns MTW = 8/NPQ m-tiles x all POS positions (NPT tiles).
template <int CIN, int HH, int WW, int POS, int KWAVES, int MINW,
          bool ASTAGE, bool OMS>
__global__ __launch_bounds__((POS / 16) * KWAVES * 64, MINW) void dcn_mfma_kernel(
    const float* __restrict__ xin,   // (B, CIN, HH, WW)
    const float* __restrict__ om,    // (B, 27, HH, WW)
    const float* __restrict__ omB,   // partial (OMS only)
    const ushort* __restrict__ whi,  // (128, K) bf16 hi, fragment order
    const ushort* __restrict__ wlo,  // (128, K) bf16 lo, fragment order
    const float* __restrict__ bias,
    const float* __restrict__ gam, const float* __restrict__ bet,
    const float* __restrict__ mu,  const float* __restrict__ var,
    float* __restrict__ out)         // (B, 128, HH*WW)
{
    constexpr int HW   = HH * WW;
    constexpr int K    = CIN * 9;
    constexpr int NPQ  = POS / 16;
    constexpr int NT   = NPQ * KWAVES * 64;
    constexpr int KC   = 32;
    constexpr int KS   = 40;
    constexpr int NCHT = K / KC;
    constexpr int NCH  = NCHT / KWAVES;
    constexpr int SBUF = POS * KS;
    constexpr int MTW  = 8 / NPQ;             // m-tiles per wave
    constexpr int NPT  = POS / 16;            // pos-tiles per wave

    extern __shared__ __align__(16) char smem[];
    uint*    eoff2 = (uint*)smem;
    float4*  ewt   = (float4*)(eoff2 + 9 * POS);
    float*   invp  = (float*)(ewt + 9 * POS);
    float*   shp   = invp + 128;
    ushort*  Sbase = (ushort*)(shp + 128);

    const int tid = threadIdx.x;
    const int nt  = HW / POS;
    const int cpx = gridDim.x >> 3;
    const int bid = (blockIdx.x & 7) * cpx + (blockIdx.x >> 3);
    const int b   = bid / nt;
    const int p0  = (bid - b * nt) * POS;

    const float* omb  = om + (size_t)b * 27 * HW;
    const float* ombB = OMS ? (omB + (size_t)b * 27 * HW) : nullptr;
    for (int i = tid; i < 9 * POS; i += NT) {
        const int k9 = i / POS, pp = i - k9 * POS;
        const int p  = p0 + pp;
        const int yy = p / WW;
        const int xx = p - yy * WW;
        float oy = omb[(size_t)k9 * HW + p];
        float ox = omb[(size_t)(9 + k9) * HW + p];
        float mv = omb[(size_t)(18 + k9) * HW + p];
        if constexpr (OMS) {
            oy += ombB[(size_t)k9 * HW + p];
            ox += ombB[(size_t)(9 + k9) * HW + p];
            mv += ombB[(size_t)(18 + k9) * HW + p];
        }
        const float m  = 1.0f / (1.0f + expf(-mv));
        const int ky = (k9 * 11) >> 5;
        const int kx = k9 - ky * 3;
        const float py = (float)(yy + ky - 1) + oy;
        const float px = (float)(xx + kx - 1) + ox;
        const float y0f = floorf(py), x0f = floorf(px);
        const int   y0  = (int)y0f,  x0 = (int)x0f;
        const int by0 = min(max(y0, 0), HH - 1);
        const int by1 = min(max(y0 + 1, 0), HH - 1);
        const int bx  = min(max(x0, 0), WW - 2);
        const float wy1 = py - y0f, wx1 = px - x0f;
        const float fy0 = (y0 >= 0  && y0 < HH)     ? (1.f - wy1) * m : 0.f;
        const float fy1 = (y0 >= -1 && y0 < HH - 1) ? wy1 * m         : 0.f;
        const float fx0v = 1.f - wx1, fx1v = wx1;
        float gx0 = 0.f, gx1 = 0.f;
        if (x0 >= 0 && x0 < WW)         { if (x0 == bx)     gx0 += fx0v; else gx1 += fx0v; }
        if (x0 + 1 >= 0 && x0 + 1 < WW) { if (x0 + 1 == bx) gx0 += fx1v; else gx1 += fx1v; }
        eoff2[i] = (uint)(by0 * WW + bx) | ((uint)(by1 * WW + bx) << 16);
        float4 wv; wv.x = fy0 * gx0; wv.y = fy0 * gx1;
                   wv.z = fy1 * gx0; wv.w = fy1 * gx1;
        ewt[i] = wv;
    }
    for (int i = tid; i < 128; i += NT) {
        const float iv = gam[i] * rsqrtf(var[i] + EPSV);
        invp[i] = iv;
        shp[i]  = bet[i] - mu[i] * iv + bias[i] * iv;
    }
    __syncthreads();

    const float* xb   = xin + (size_t)b * CIN * HW;
    const int lane = tid & 63;
    const int w    = tid >> 6;
    const int wm   = w & (NPQ - 1);          // m-group of this wave
    const int kgid = w / NPQ;
    const int tt   = tid & (NPQ * 64 - 1);
    const int m0   = wm * MTW;

    f32x4 acc[8];                             // [mt2][pt] flattened
#pragma unroll
    for (int mt = 0; mt < 8; ++mt) acc[mt] = (f32x4){0.f, 0.f, 0.f, 0.f};

    const int mrow = lane & 15;
    const int kq   = lane >> 4;

    if constexpr (ASTAGE) {
        // ===== S DOUBLE-buffer, A JIT, ONE barrier per chunk ==========
        // chunk body: {A-JIT + MFMA from S[cur]} || {finish(ch+1)->S[cur^1],
        // issue(ch+2)} -> lgkm barrier.  Reads of S[cur] and the next write
        // to S[cur] are separated by exactly one barrier.
        float2 v0[8], v1[8];
        sample_chunk<CIN, HH, WW, POS, KS>(xb, eoff2, ewt,
                                           Sbase, Sbase + SBUF, tt, 0);
        if (NCH > 1)
            sample_issue<CIN, HH, WW, POS>(xb, eoff2, v0, v1, tt, KC);
        asm volatile("s_waitcnt lgkmcnt(0)" ::: "memory");
        __builtin_amdgcn_s_barrier();
        __builtin_amdgcn_sched_barrier(0);

        for (int ch = 0; ch < NCH; ++ch) {
            const int cur = ch & 1;
            ushort* Rhi = Sbase + (cur * 2) * SBUF;
            ushort* Rlo = Rhi + SBUF;
            // ---- MFMA: A JIT from global (L2-hot), B from S[cur] ----
            const size_t abase = (size_t)(ch * 8) * 512;
            short8 ahv[MTW], alv[MTW];
            __builtin_amdgcn_s_setprio(1);
#pragma unroll
            for (int mt2 = 0; mt2 < MTW; ++mt2) {
                const size_t ao = abase + (size_t)(((m0 + mt2) * 64 + lane) * 8);
                ahv[mt2] = *(const short8*)(whi + ao);
                alv[mt2] = *(const short8*)(wlo + ao);
            }
#pragma unroll
            for (int pt = 0; pt < NPT; ++pt) {
                const int boff = (pt * 16 + mrow) * KS + kq * 8;
                const short8 bh = *(const short8*)&Rhi[boff];
                const short8 bl = *(const short8*)&Rlo[boff];
#pragma unroll
                for (int mt2 = 0; mt2 < MTW; ++mt2) {
                    f32x4 a = acc[mt2 * NPT + pt];
                    a = __builtin_amdgcn_mfma_f32_16x16x32_bf16(alv[mt2], bh, a, 0, 0, 0);
                    a = __builtin_amdgcn_mfma_f32_16x16x32_bf16(ahv[mt2], bl, a, 0, 0, 0);
                    a = __builtin_amdgcn_mfma_f32_16x16x32_bf16(ahv[mt2], bh, a, 0, 0, 0);
                    acc[mt2 * NPT + pt] = a;
                }
            }
            __builtin_amdgcn_s_setprio(0);
            // ---- same phase: finish(ch+1) -> S[cur^1], issue(ch+2) ----
            if (ch + 1 < NCH) {
                ushort* Whi_ = Sbase + ((cur ^ 1) * 2) * SBUF;
                ushort* Wlo_ = Whi_ + SBUF;
                sample_finish<CIN, HH, WW, POS, KS>(ewt, v0, v1, Whi_, Wlo_,
                                                    tt, (ch + 1) * KC);
                if (ch + 2 < NCH)
                    sample_issue<CIN, HH, WW, POS>(xb, eoff2, v0, v1, tt,
                                                   (ch + 2) * KC);
            }
            asm volatile("s_waitcnt lgkmcnt(0)" ::: "memory");
            __builtin_amdgcn_s_barrier();
            __builtin_amdgcn_sched_barrier(0);
        }
    } else {
        ushort* S00 = Sbase + kgid * (4 * SBUF);
        sample_chunk<CIN, HH, WW, POS, KS>(xb, eoff2, ewt, S00, S00 + SBUF,
                                           tt, kgid * NCH * KC);
        __syncthreads();

        for (int ch = 0; ch < NCH; ++ch) {
            const int cur = ch & 1;
            ushort* Sc = S00 + (cur * 2) * SBUF;
            // B fragments for all pos-tiles (held across the sampler)
            short8 bhv[NPT], blv[NPT];
#pragma unroll
            for (int pt = 0; pt < NPT; ++pt) {
                const int boff = (pt * 16 + mrow) * KS + kq * 8;
                bhv[pt] = *(const short8*)&Sc[boff];
                blv[pt] = *(const short8*)&Sc[SBUF + boff];
            }
            if (ch + 1 < NCH) {
                ushort* Sn = S00 + ((cur ^ 1) * 2) * SBUF;
                sample_chunk<CIN, HH, WW, POS, KS>(xb, eoff2, ewt,
                                                   Sn, Sn + SBUF, tt,
                                                   (kgid * NCH + ch + 1) * KC);
            }
            // A fragments just-in-time from global (fragment order, coalesced)
            const size_t abase = (size_t)((kgid * NCH + ch) * 8) * 512;
            __builtin_amdgcn_s_setprio(1);
#pragma unroll
            for (int mt2 = 0; mt2 < MTW; ++mt2) {
                const size_t ao = abase + (size_t)(((m0 + mt2) * 64 + lane) * 8);
                const short8 ah = *(const short8*)(whi + ao);
                const short8 al = *(const short8*)(wlo + ao);
#pragma unroll
                for (int pt = 0; pt < NPT; ++pt) {
                    f32x4 a = acc[mt2 * NPT + pt];
                    a = __builtin_amdgcn_mfma_f32_16x16x32_bf16(al, bhv[pt], a, 0, 0, 0);
                    a = __builtin_amdgcn_mfma_f32_16x16x32_bf16(ah, blv[pt], a, 0, 0, 0);
                    a = __builtin_amdgcn_mfma_f32_16x16x32_bf16(ah, bhv[pt], a, 0, 0, 0);
                    acc[mt2 * NPT + pt] = a;
                }
            }
            __builtin_amdgcn_s_setprio(0);
            __syncthreads();
        }
    }

    constexpr int RS = POS + 1;
    constexpr int SL = 128 * RS;
    float* red = (float*)Sbase;

    if constexpr (KWAVES == 4) {
        if (kgid >= 2) {
#pragma unroll
            for (int mt2 = 0; mt2 < MTW; ++mt2)
#pragma unroll
                for (int pt = 0; pt < NPT; ++pt)
#pragma unroll
                    for (int r = 0; r < 4; ++r) {
                        const int co = (m0 + mt2) * 16 + kq * 4 + r;
                        red[(kgid - 2) * SL + co * RS + pt * 16 + mrow] =
                            acc[mt2 * NPT + pt][r];
                    }
        }
        __syncthreads();
        if (kgid < 2) {
#pragma unroll
            for (int mt2 = 0; mt2 < MTW; ++mt2)
#pragma unroll
                for (int pt = 0; pt < NPT; ++pt)
#pragma unroll
                    for (int r = 0; r < 4; ++r) {
                        const int co = (m0 + mt2) * 16 + kq * 4 + r;
                        acc[mt2 * NPT + pt][r] +=
                            red[kgid * SL + co * RS + pt * 16 + mrow];
                    }
        }
        __syncthreads();
        if (kgid == 1) {
#pragma unroll
            for (int mt2 = 0; mt2 < MTW; ++mt2)
#pragma unroll
                for (int pt = 0; pt < NPT; ++pt)
#pragma unroll
                    for (int r = 0; r < 4; ++r) {
                        const int co = (m0 + mt2) * 16 + kq * 4 + r;
                        red[co * RS + pt * 16 + mrow] = acc[mt2 * NPT + pt][r];
                    }
        }
        __syncthreads();
        if (kgid == 0) {
#pragma unroll
            for (int mt2 = 0; mt2 < MTW; ++mt2)
#pragma unroll
                for (int pt = 0; pt < NPT; ++pt)
#pragma unroll
                    for (int r = 0; r < 4; ++r) {
                        const int co = (m0 + mt2) * 16 + kq * 4 + r;
                        acc[mt2 * NPT + pt][r] += red[co * RS + pt * 16 + mrow];
                    }
        }
    } else if constexpr (KWAVES == 2) {
        if (kgid == 1) {
#pragma unroll
            for (int mt2 = 0; mt2 < MTW; ++mt2)
#pragma unroll
                for (int pt = 0; pt < NPT; ++pt)
#pragma unroll
                    for (int r = 0; r < 4; ++r) {
                        const int co = (m0 + mt2) * 16 + kq * 4 + r;
                        red[co * RS + pt * 16 + mrow] = acc[mt2 * NPT + pt][r];
                    }
        }
        __syncthreads();
        if (kgid == 0) {
#pragma unroll
            for (int mt2 = 0; mt2 < MTW; ++mt2)
#pragma unroll
                for (int pt = 0; pt < NPT; ++pt)
#pragma unroll
                    for (int r = 0; r < 4; ++r) {
                        const int co = (m0 + mt2) * 16 + kq * 4 + r;
                        acc[mt2 * NPT + pt][r] += red[co * RS + pt * 16 + mrow];
                    }
        }
    }

    if (kgid == 0) {
        float* outb = out + (size_t)b * 128 * HW + p0;
#pragma unroll
        for (int mt2 = 0; mt2 < MTW; ++mt2)
#pragma unroll
            for (int pt = 0; pt < NPT; ++pt)
#pragma unroll
                for (int r = 0; r < 4; ++r) {
                    const int co = (m0 + mt2) * 16 + kq * 4 + r;
                    outb[(size_t)co * HW + pt * 16 + mrow] =
                        fmaxf(acc[mt2 * NPT + pt][r] * invp[co] + shp[co], 0.f);
                }
    }
}

// ---------------- depthwise transposed-conv upsample x2 (k=4, pad 2) --------
__global__ __launch_bounds__(256) void upsample_kernel(
    const float* __restrict__ y,    // (4,128,64,64)
    const float* __restrict__ wup,  // (128,1,4,4)
    float* __restrict__ out)        // (4,128,128,128)
{
    const int idx = blockIdx.x * 256 + threadIdx.x;
    const int ox = idx & 127;
    const int oy = (idx >> 7) & 127;
    const int c  = (idx >> 14) & 127;
    const int b  = idx >> 21;

    const float* yc = y + (size_t)(b * 128 + c) * 4096;
    const float* wc = wup + c * 16;

    float acc = 0.f;
#pragma unroll
    for (int ky = 0; ky < 4; ++ky) {
        const int qy = oy + ky - 2;
        if (qy & 1) continue;
        const int iy = qy >> 1;
        if (iy < 0 || iy >= 64) continue;
#pragma unroll
        for (int kx = 0; kx < 4; ++kx) {
            const int qx = ox + kx - 2;
            if (qx & 1) continue;
            const int ix = qx >> 1;
            if (ix < 0 || ix >= 64) continue;
            acc += yc[iy * 64 + ix] * wc[(3 - ky) * 4 + (3 - kx)];
        }
    }
    out[idx] = acc;
}

// ---------------------------------------------------------------------------
extern "C" void kernel_launch(void* const* d_in, const int* in_sizes, int n_in,
                              void* d_out, int out_size, void* d_ws, size_t ws_size,
                              hipStream_t stream) {
    const float* x      = (const float*)d_in[0];
    const float* w_off1 = (const float*)d_in[1];
    const float* b_off1 = (const float*)d_in[2];
    const float* w1     = (const float*)d_in[3];
    const float* b1     = (const float*)d_in[4];
    const float* g1v    = (const float*)d_in[5];
    const float* be1    = (const float*)d_in[6];
    const float* m1     = (const float*)d_in[7];
    const float* v1     = (const float*)d_in[8];
    const float* w_up   = (const float*)d_in[9];
    const float* w_off2 = (const float*)d_in[10];
    const float* b_off2 = (const float*)d_in[11];
    const float* w2     = (const float*)d_in[12];
    const float* b2     = (const float*)d_in[13];
    const float* g2v    = (const float*)d_in[14];
    const float* be2    = (const float*)d_in[15];
    const float* m2     = (const float*)d_in[16];
    const float* v2     = (const float*)d_in[17];

    float* ws  = (float*)d_ws;
    float* om1 = ws;                     // 4*27*4096   =   442368 f
    float* y1  = om1 + 442368;           // 4*128*4096  =  2097152 f
    float* up  = y1 + 2097152;           // 4*128*16384 =  8388608 f
    float* om2 = up + 8388608;           // 4*27*16384  =  1769472 f
    float* outf = (float*)d_out;

    // `up` region (dead until upsample writes it): w1 + w_off1 splits
    ushort* w1hi  = (ushort*)up;         // 294912
    ushort* w1lo  = w1hi + 294912;       // 294912
    ushort* wo1hi = w1lo + 294912;       // 32*2304 = 73728
    ushort* wo1lo = wo1hi + 73728;       // 73728
    // `y1` region (dead after upsample reads it): w2 + w_off2 splits
    ushort* w2hi  = (ushort*)y1;         // 147456
    ushort* w2lo  = w2hi + 147456;       // 147456
    ushort* wo2hi = w2lo + 147456;       // 32*1152 = 36864
    ushort* wo2lo = wo2hi + 36864;       // 36864

    // prep: w1 (dcn1) + w_off1 (conv1) splits, fragment order
    wsplit_perm_kernel<<<(294912 + 255) / 256, 256, 0, stream>>>(
        w1, w1hi, w1lo, 256, 294912);
    wsplit_perm_conv_kernel<<<(73728 + 255) / 256, 256, 0, stream>>>(
        w_off1, wo1hi, wo1lo, 256, 73728);

    // om1 = conv3x3(x, w_off1) + b_off1 — MFMA, POS=16, KWAVES=4
    conv_mfma_kernel<256, 64, 64, 16, 4, 4>
        <<<1024, 256, 21632, stream>>>(x, wo1hi, wo1lo, b_off1, om1);

    // y1 = bn_relu(dcn1) — MFMA, POS=32, 4-way K-split, M-split waves
    dcn_mfma_kernel<256, 64, 64, 32, 4, 4, false, false>
        <<<4 * (4096 / 32), 512, 47744, stream>>>(
        x, om1, om1, w1hi, w1lo, b1, g1v, be1, m1, v1, y1);
    // up = depthwise transposed upsample (clobbers w1/wo1 splits — now dead)
    upsample_kernel<<<8388608 / 256, 256, 0, stream>>>(y1, w_up, up);

    // prep: w2 (dcn2) + w_off2 (conv2) splits (y1 now dead)
    wsplit_perm_kernel<<<(147456 + 255) / 256, 256, 0, stream>>>(
        w2, w2hi, w2lo, 128, 147456);
    wsplit_perm_conv_kernel<<<(36864 + 255) / 256, 256, 0, stream>>>(
        w_off2, wo2hi, wo2lo, 128, 36864);

    // om2 = conv3x3(up, w_off2) + b_off2 — MFMA, POS=64, KWAVES=1
    conv_mfma_kernel<128, 128, 128, 64, 1, 4>
        <<<1024, 256, 25088, stream>>>(up, wo2hi, wo2lo, b_off2, om2);

    // out = bn_relu(dcn2) — MFMA, POS=64, A JIT, S double-buffer, 1 barrier
    // LDS: 2304 + 9216 + 1024 + 2*10240 = 33024 -> 4 blocks/CU
    dcn_mfma_kernel<128, 128, 128, 64, 1, 4, true, false>
        <<<4 * (16384 / 64), 256, 33024, stream>>>(
        up, om2, om2, w2hi, w2lo, b2, g2v, be2, m2, v2, outf);
}

// Round 20
// 359.532 us; speedup vs baseline: 1.0208x; 1.0208x over previous
//
#include <hip/hip_runtime.h>
#include <hip/hip_bf16.h>
#include <cmath>

// ---------------------------------------------------------------------------
// Pipeline: y1 = bn_relu(dcn(x, w_off1, b_off1, w1, b1))        (4,128,64,64)
//           up = up_depthwise(y1, w_up, f=2)                    (4,128,128,128)
//           out = bn_relu(dcn(up, w_off2, b_off2, w2, b2))      (4,128,128,128)
// ALL GEMM-shaped work on mfma_f32_16x16x32_bf16, split-bf16 (hi/lo, 3 prod).
// BEST VERIFIED CONFIG (R15, 358.2us): dcn2 A-stage T14-split — A global
// loads for ch+1 issued into regs BEFORE the pre-MFMA barrier (a full MFMA
// phase to land); write phase only ds_writes from regs. M-split wave mapping
// (A frags read once/chunk, reused over pos-tiles). pack via
// v_cvt_pk_bf16_f32; s_setprio(1) around MFMA clusters.
// conv_off -> conv_mfma (M=27 padded to 32, tap-sampler B).
// Weights pre-permuted into per-chunk fragment order (coalesced A loads).
// Workspace: om1 | y1 | up | om2 ; w1+wo1 splits parked in `up`,
// w2+wo2 splits parked in `y1`.
// Depth-2 gather pipelining is DEAD: spills at MINW=4 (R16), fails
// validation at MINW=3 (R19). A-JIT and 1-barrier dbuf measured neutral
// (R17/R18). This structure is the measured floor at 4 blocks/CU.
// ---------------------------------------------------------------------------

#define EPSV 1e-5f

typedef __attribute__((ext_vector_type(8))) short short8;
typedef __attribute__((ext_vector_type(4))) float f32x4;

__device__ __forceinline__ ushort f2bf(float f) {
    union { float f; uint u; } v; v.f = f;
    const uint r = v.u + 0x7fffu + ((v.u >> 16) & 1u);   // RNE
    return (ushort)(r >> 16);
}
__device__ __forceinline__ float bf2f(ushort h) {
    union { uint u; float f; } v; v.u = ((uint)h) << 16;
    return v.f;
}
__device__ __forceinline__ float2 ld2u(const float* p) {
    float2 v; __builtin_memcpy(&v, p, sizeof(float2)); return v;
}
// packed bf16 RNE convert: dst.lo = bf16(a), dst.hi = bf16(b)
__device__ __forceinline__ uint cvtpk_bf16(float a, float b) {
    uint r;
    asm("v_cvt_pk_bf16_f32 %0, %1, %2" : "=v"(r) : "v"(a), "v"(b));
    return r;
}

// ---- pack 8 fp32 -> bf16 hi/lo rows of S (cvt_pk fast path) ----------------
template <int KS>
__device__ __forceinline__ void pack_store8(
    const float* s, ushort* __restrict__ Shi, ushort* __restrict__ Slo,
    int pp, int j0)
{
    uint hw[4], lw[4];
#pragma unroll
    for (int q = 0; q < 4; ++q) {
        const float s0 = s[2 * q], s1 = s[2 * q + 1];
        const uint h = cvtpk_bf16(s0, s1);
        union { uint u; float f; } h0, h1;
        h0.u = h << 16;
        h1.u = h & 0xffff0000u;
        hw[q] = h;
        lw[q] = cvtpk_bf16(s0 - h0.f, s1 - h1.f);
    }
    uint4 hv; hv.x = hw[0]; hv.y = hw[1]; hv.z = hw[2]; hv.w = hw[3];
    uint4 lv; lv.x = lw[0]; lv.y = lw[1]; lv.z = lw[2]; lv.w = lw[3];
    *(uint4*)&Shi[pp * KS + j0] = hv;
    *(uint4*)&Slo[pp * KS + j0] = lv;
}

// ------- weight split: fp32 -> bf16 hi/lo in per-chunk FRAGMENT order -------
__global__ __launch_bounds__(256) void wsplit_perm_kernel(
    const float* __restrict__ w, ushort* __restrict__ hi,
    ushort* __restrict__ lo, int cin, int n)
{
    const int i = blockIdx.x * 256 + threadIdx.x;
    if (i >= n) return;
    const int cin9 = cin * 9;
    const int co = i / cin9;
    const int k  = i - co * cin9;            // channel-major K index
    const int ch = k >> 5;
    const int kq = (k & 31) >> 3;
    const int j  = k & 7;
    const int mt = co >> 4;
    const int lane = (co & 15) | (kq << 4);
    const size_t dst = ((size_t)(ch * 8 + mt) * 64 + lane) * 8 + j;
    const float f = w[i];
    const ushort h = f2bf(f);
    hi[dst] = h;
    lo[dst] = f2bf(f - bf2f(h));
}

// ------- conv weight split: (27,CIN,3,3) -> M=32 zero-padded frag order -----
__global__ __launch_bounds__(256) void wsplit_perm_conv_kernel(
    const float* __restrict__ w, ushort* __restrict__ hi,
    ushort* __restrict__ lo, int cin, int n)   // n = 32*cin*9
{
    const int i = blockIdx.x * 256 + threadIdx.x;
    if (i >= n) return;
    const int cin9 = cin * 9;
    const int co = i / cin9;
    const int k  = i - co * cin9;
    const int ch = k >> 5;
    const int kq = (k & 31) >> 3;
    const int j  = k & 7;
    const int mt = co >> 4;
    const int lane = (co & 15) | (kq << 4);
    const size_t dst = ((size_t)(ch * 2 + mt) * 64 + lane) * 8 + j;
    const float f = (co < 27) ? w[(size_t)co * cin9 + k] : 0.f;
    const ushort h = f2bf(f);
    hi[dst] = h;
    lo[dst] = f2bf(f - bf2f(h));
}

// ---------------- offset conv on MFMA: 3x3, pad 1, 27(->32) outputs ---------
template <int CIN, int HH, int WW, int POS, int KS>
__device__ __forceinline__ void conv_sample_chunk(
    const float* __restrict__ xb, const uint* __restrict__ toff,
    const float* __restrict__ twt, ushort* __restrict__ Shi,
    ushort* __restrict__ Slo, int tt, int kbase)
{
    constexpr int HW = HH * WW;
    const int pp = tt & (POS - 1);
    const int j0 = (tt / POS) * 8;
    float s[8];
#pragma unroll
    for (int j = 0; j < 8; ++j) {
        const int kg = kbase + j0 + j;
        const int c  = (kg * 7282) >> 16;       // /9 (exact for kg<2304)
        const int k9 = kg - c * 9;
        const int ei = k9 * POS + pp;
        s[j] = xb[(size_t)c * HW + toff[ei]] * twt[ei];
    }
    pack_store8<KS>(s, Shi, Slo, pp, j0);
}

template <int CIN, int HH, int WW, int POS, int KWAVES, int MINW>
__global__ __launch_bounds__((POS / 16) * KWAVES * 64, MINW) void conv_mfma_kernel(
    const float* __restrict__ in,    // (B, CIN, HH, WW)
    const ushort* __restrict__ whi,  // (32, CIN*9) frag order, zero-padded
    const ushort* __restrict__ wlo,
    const float* __restrict__ bias,  // (27)
    float* __restrict__ om)          // (B, 27, HH*WW)
{
    constexpr int HW   = HH * WW;
    constexpr int K    = CIN * 9;
    constexpr int NPQ  = POS / 16;
    constexpr int NT   = NPQ * KWAVES * 64;
    constexpr int KC   = 32;
    constexpr int KS   = 40;
    constexpr int NCHT = K / KC;
    constexpr int NCH  = NCHT / KWAVES;
    constexpr int SBUF = POS * KS;

    extern __shared__ __align__(16) char smem[];
    uint*   toff  = (uint*)smem;              // 9*POS
    float*  twt   = (float*)(toff + 9 * POS); // 9*POS
    ushort* Sbase = (ushort*)(twt + 9 * POS);

    const int tid = threadIdx.x;
    const int nt  = HW / POS;
    const int cpx = gridDim.x >> 3;
    const int bid = (blockIdx.x & 7) * cpx + (blockIdx.x >> 3);
    const int b   = bid / nt;
    const int p0  = (bid - b * nt) * POS;

    for (int i = tid; i < 9 * POS; i += NT) {
        const int k9 = i / POS, pp = i - k9 * POS;
        const int p  = p0 + pp;
        const int yy = p / WW, xx = p - yy * WW;
        const int ky = (k9 * 11) >> 5, kx = k9 - ky * 3;
        const int iy = yy + ky - 1, ix = xx + kx - 1;
        const bool v = (iy >= 0) && (iy < HH) && (ix >= 0) && (ix < WW);
        const int cy = min(max(iy, 0), HH - 1);
        const int cx = min(max(ix, 0), WW - 1);
        toff[i] = (uint)(cy * WW + cx);
        twt[i]  = v ? 1.f : 0.f;
    }
    __syncthreads();

    const float* xb = in + (size_t)b * CIN * HW;
    const int lane = tid & 63;
    const int w    = tid >> 6;
    const int wq   = w & (NPQ - 1);
    const int kgid = w / NPQ;
    const int tt   = tid & (NPQ * 64 - 1);
    ushort* S00 = Sbase + kgid * (4 * SBUF);

    f32x4 acc[2];
    acc[0] = (f32x4){0.f, 0.f, 0.f, 0.f};
    acc[1] = (f32x4){0.f, 0.f, 0.f, 0.f};
    const int mrow = lane & 15;
    const int kq   = lane >> 4;

    conv_sample_chunk<CIN, HH, WW, POS, KS>(xb, toff, twt, S00, S00 + SBUF,
                                            tt, kgid * NCH * KC);
    __syncthreads();

    for (int ch = 0; ch < NCH; ++ch) {
        const int cur = ch & 1;
        ushort* Sc = S00 + (cur * 2) * SBUF;
        const int boff = (wq * 16 + mrow) * KS + kq * 8;
        const short8 bh = *(const short8*)&Sc[boff];
        const short8 bl = *(const short8*)&Sc[SBUF + boff];
        if (ch + 1 < NCH) {
            ushort* Sn = S00 + ((cur ^ 1) * 2) * SBUF;
            conv_sample_chunk<CIN, HH, WW, POS, KS>(xb, toff, twt,
                                                    Sn, Sn + SBUF, tt,
                                                    (kgid * NCH + ch + 1) * KC);
        }
        const size_t abase = (size_t)((kgid * NCH + ch) * 2) * 512;
        __builtin_amdgcn_s_setprio(1);
#pragma unroll
        for (int mt = 0; mt < 2; ++mt) {
            const size_t ao = abase + (size_t)((mt * 64 + lane) * 8);
            const short8 ah = *(const short8*)(whi + ao);
            const short8 al = *(const short8*)(wlo + ao);
            acc[mt] = __builtin_amdgcn_mfma_f32_16x16x32_bf16(al, bh, acc[mt], 0, 0, 0);
            acc[mt] = __builtin_amdgcn_mfma_f32_16x16x32_bf16(ah, bl, acc[mt], 0, 0, 0);
            acc[mt] = __builtin_amdgcn_mfma_f32_16x16x32_bf16(ah, bh, acc[mt], 0, 0, 0);
        }
        __builtin_amdgcn_s_setprio(0);
        __syncthreads();
    }

    const int pcolb = wq * 16 + mrow;
    constexpr int RS = POS + 1;
    constexpr int SL = 32 * RS;
    float* red = (float*)Sbase;

    if constexpr (KWAVES == 4) {
        if (kgid >= 2) {
#pragma unroll
            for (int mt = 0; mt < 2; ++mt)
#pragma unroll
                for (int r = 0; r < 4; ++r) {
                    const int co = mt * 16 + kq * 4 + r;
                    red[(kgid - 2) * SL + co * RS + pcolb] = acc[mt][r];
                }
        }
        __syncthreads();
        if (kgid < 2) {
#pragma unroll
            for (int mt = 0; mt < 2; ++mt)
#pragma unroll
                for (int r = 0; r < 4; ++r) {
                    const int co = mt * 16 + kq * 4 + r;
                    acc[mt][r] += red[kgid * SL + co * RS + pcolb];
                }
        }
        __syncthreads();
        if (kgid == 1) {
#pragma unroll
            for (int mt = 0; mt < 2; ++mt)
#pragma unroll
                for (int r = 0; r < 4; ++r) {
                    const int co = mt * 16 + kq * 4 + r;
                    red[co * RS + pcolb] = acc[mt][r];
                }
        }
        __syncthreads();
        if (kgid == 0) {
#pragma unroll
            for (int mt = 0; mt < 2; ++mt)
#pragma unroll
                for (int r = 0; r < 4; ++r) {
                    const int co = mt * 16 + kq * 4 + r;
                    acc[mt][r] += red[co * RS + pcolb];
                }
        }
    } else if constexpr (KWAVES == 2) {
        if (kgid == 1) {
#pragma unroll
            for (int mt = 0; mt < 2; ++mt)
#pragma unroll
                for (int r = 0; r < 4; ++r) {
                    const int co = mt * 16 + kq * 4 + r;
                    red[co * RS + pcolb] = acc[mt][r];
                }
        }
        __syncthreads();
        if (kgid == 0) {
#pragma unroll
            for (int mt = 0; mt < 2; ++mt)
#pragma unroll
                for (int r = 0; r < 4; ++r) {
                    const int co = mt * 16 + kq * 4 + r;
                    acc[mt][r] += red[co * RS + pcolb];
                }
        }
    }

    if (kgid == 0) {
        float* ob = om + (size_t)b * 27 * HW + p0 + pcolb;
#pragma unroll
        for (int mt = 0; mt < 2; ++mt)
#pragma unroll
            for (int r = 0; r < 4; ++r) {
                const int co = mt * 16 + kq * 4 + r;
                if (co < 27)
                    ob[(size_t)co * HW] = acc[mt][r] + bias[co];
            }
    }
}

// ---------------- paired sampler: issue / finish ----------------------------
template <int CIN, int HH, int WW, int POS>
__device__ __forceinline__ void sample_issue(
    const float* __restrict__ xb, const uint* __restrict__ eoff2,
    float2* v0, float2* v1, int tt, int kbase)
{
    constexpr int HW = HH * WW;
    const int pp = tt & (POS - 1);
    const int j0 = (tt / POS) * 8;
#pragma unroll
    for (int j = 0; j < 8; ++j) {
        const int kg = kbase + j0 + j;
        const int c  = (kg * 7282) >> 16;       // /9 (exact for kg<2304)
        const int k9 = kg - c * 9;
        const uint e = eoff2[k9 * POS + pp];
        const float* chp = xb + (size_t)c * HW;
        v0[j] = ld2u(chp + (e & 0xffffu));
        v1[j] = ld2u(chp + (e >> 16));
    }
}

template <int CIN, int HH, int WW, int POS, int KS>
__device__ __forceinline__ void sample_finish(
    const float4* __restrict__ ewt, const float2* v0, const float2* v1,
    ushort* __restrict__ Shi, ushort* __restrict__ Slo, int tt, int kbase)
{
    const int pp = tt & (POS - 1);
    const int j0 = (tt / POS) * 8;
    float s[8];
#pragma unroll
    for (int j = 0; j < 8; ++j) {
        const int kg = kbase + j0 + j;
        const int c  = (kg * 7282) >> 16;
        const int k9 = kg - c * 9;
        const float4 wv = ewt[k9 * POS + pp];
        s[j] = v0[j].x * wv.x + v0[j].y * wv.y
             + v1[j].x * wv.z + v1[j].y * wv.w;
    }
    pack_store8<KS>(s, Shi, Slo, pp, j0);
}

template <int CIN, int HH, int WW, int POS, int KS>
__device__ __forceinline__ void sample_chunk(
    const float* __restrict__ xb, const uint* __restrict__ eoff2,
    const float4* __restrict__ ewt, ushort* __restrict__ Shi,
    ushort* __restrict__ Slo, int tt, int kbase)
{
    float2 v0[8], v1[8];
    sample_issue<CIN, HH, WW, POS>(xb, eoff2, v0, v1, tt, kbase);
    sample_finish<CIN, HH, WW, POS, KS>(ewt, v0, v1, Shi, Slo, tt, kbase);
}

// ---------------- fused DCN on MFMA: sample + GEMM + bias + BN + ReLU -------
// M-SPLIT: wave wm owns MTW = 8/NPQ m-tiles x all POS positions (NPT tiles).
template <int CIN, int HH, int WW, int POS, int KWAVES, int MINW,
          bool ASTAGE, bool OMS>
__global__ __launch_bounds__((POS / 16) * KWAVES * 64, MINW) void dcn_mfma_kernel(
    const float* __restrict__ xin,   // (B, CIN, HH, WW)
    const float* __restrict__ om,    // (B, 27, HH, WW)
    const float* __restrict__ omB,   // partial (OMS only)
    const ushort* __restrict__ whi,  // (128, K) bf16 hi, fragment order
    const ushort* __restrict__ wlo,  // (128, K) bf16 lo, fragment order
    const float* __restrict__ bias,
    const float* __restrict__ gam, const float* __restrict__ bet,
    const float* __restrict__ mu,  const float* __restrict__ var,
    float* __restrict__ out)         // (B, 128, HH*WW)
{
    constexpr int HW   = HH * WW;
    constexpr int K    = CIN * 9;
    constexpr int NPQ  = POS / 16;
    constexpr int NT   = NPQ * KWAVES * 64;
    constexpr int KC   = 32;
    constexpr int KS   = 40;
    constexpr int NCHT = K / KC;
    constexpr int NCH  = NCHT / KWAVES;
    constexpr int SBUF = POS * KS;
    constexpr int ABN  = ASTAGE ? 8192 : 0;
    constexpr int MTW  = 8 / NPQ;             // m-tiles per wave
    constexpr int NPT  = POS / 16;            // pos-tiles per wave

    extern __shared__ __align__(16) char smem[];
    uint*    eoff2 = (uint*)smem;
    float4*  ewt   = (float4*)(eoff2 + 9 * POS);
    float*   invp  = (float*)(ewt + 9 * POS);
    float*   shp   = invp + 128;
    ushort*  Abuf  = (ushort*)(shp + 128);
    ushort*  Sbase = Abuf + ABN;

    const int tid = threadIdx.x;
    const int nt  = HW / POS;
    const int cpx = gridDim.x >> 3;
    const int bid = (blockIdx.x & 7) * cpx + (blockIdx.x >> 3);
    const int b   = bid / nt;
    const int p0  = (bid - b * nt) * POS;

    const float* omb  = om + (size_t)b * 27 * HW;
    const float* ombB = OMS ? (omB + (size_t)b * 27 * HW) : nullptr;
    for (int i = tid; i < 9 * POS; i += NT) {
        const int k9 = i / POS, pp = i - k9 * POS;
        const int p  = p0 + pp;
        const int yy = p / WW;
        const int xx = p - yy * WW;
        float oy = omb[(size_t)k9 * HW + p];
        float ox = omb[(size_t)(9 + k9) * HW + p];
        float mv = omb[(size_t)(18 + k9) * HW + p];
        if constexpr (OMS) {
            oy += ombB[(size_t)k9 * HW + p];
            ox += ombB[(size_t)(9 + k9) * HW + p];
            mv += ombB[(size_t)(18 + k9) * HW + p];
        }
        const float m  = 1.0f / (1.0f + expf(-mv));
        const int ky = (k9 * 11) >> 5;
        const int kx = k9 - ky * 3;
        const float py = (float)(yy + ky - 1) + oy;
        const float px = (float)(xx + kx - 1) + ox;
        const float y0f = floorf(py), x0f = floorf(px);
        const int   y0  = (int)y0f,  x0 = (int)x0f;
        const int by0 = min(max(y0, 0), HH - 1);
        const int by1 = min(max(y0 + 1, 0), HH - 1);
        const int bx  = min(max(x0, 0), WW - 2);
        const float wy1 = py - y0f, wx1 = px - x0f;
        const float fy0 = (y0 >= 0  && y0 < HH)     ? (1.f - wy1) * m : 0.f;
        const float fy1 = (y0 >= -1 && y0 < HH - 1) ? wy1 * m         : 0.f;
        const float fx0v = 1.f - wx1, fx1v = wx1;
        float gx0 = 0.f, gx1 = 0.f;
        if (x0 >= 0 && x0 < WW)         { if (x0 == bx)     gx0 += fx0v; else gx1 += fx0v; }
        if (x0 + 1 >= 0 && x0 + 1 < WW) { if (x0 + 1 == bx) gx0 += fx1v; else gx1 += fx1v; }
        eoff2[i] = (uint)(by0 * WW + bx) | ((uint)(by1 * WW + bx) << 16);
        float4 wv; wv.x = fy0 * gx0; wv.y = fy0 * gx1;
                   wv.z = fy1 * gx0; wv.w = fy1 * gx1;
        ewt[i] = wv;
    }
    for (int i = tid; i < 128; i += NT) {
        const float iv = gam[i] * rsqrtf(var[i] + EPSV);
        invp[i] = iv;
        shp[i]  = bet[i] - mu[i] * iv + bias[i] * iv;
    }
    __syncthreads();

    const float* xb   = xin + (size_t)b * CIN * HW;
    const int lane = tid & 63;
    const int w    = tid >> 6;
    const int wm   = w & (NPQ - 1);          // m-group of this wave
    const int kgid = w / NPQ;
    const int tt   = tid & (NPQ * 64 - 1);
    const int m0   = wm * MTW;

    f32x4 acc[8];                             // [mt2][pt] flattened
#pragma unroll
    for (int mt = 0; mt < 8; ++mt) acc[mt] = (f32x4){0.f, 0.f, 0.f, 0.f};

    const int mrow = lane & 15;
    const int kq   = lane >> 4;

    if constexpr (ASTAGE) {
        // ===== single-S-buffer alternating-phase pipeline (A also split) ====
        ushort* Shi = Sbase;
        ushort* Slo = Sbase + SBUF;
        float2 v0[8], v1[8];
        short8 ar0, ar1, ar2, ar3;            // A-stage regs for ch+1
        sample_chunk<CIN, HH, WW, POS, KS>(xb, eoff2, ewt, Shi, Slo, tt, 0);
        {   // stage A(0) directly (once; latency exposed only here)
#pragma unroll
            for (int t = 0; t < 1024 / NT; ++t) {
                const int u = tid + t * NT;
                const ushort* srcp = (u < 512)
                    ? (whi + (size_t)u * 8)
                    : (wlo + (size_t)(u - 512) * 8);
                *(short8*)&Abuf[(size_t)u * 8] = *(const short8*)srcp;
            }
        }
        if (NCH > 1) {
            sample_issue<CIN, HH, WW, POS>(xb, eoff2, v0, v1, tt, KC);
            // issue A-loads(1) into regs (land during MFMA phase)
            const size_t wb = (size_t)1 * 4096;
            const int u0 = tid, u1 = tid + NT, u2 = tid + 2 * NT, u3 = tid + 3 * NT;
            ar0 = *(const short8*)((u0 < 512 ? whi + wb + (size_t)u0 * 8
                                             : wlo + wb + (size_t)(u0 - 512) * 8));
            ar1 = *(const short8*)((u1 < 512 ? whi + wb + (size_t)u1 * 8
                                             : wlo + wb + (size_t)(u1 - 512) * 8));
            ar2 = *(const short8*)((u2 < 512 ? whi + wb + (size_t)u2 * 8
                                             : wlo + wb + (size_t)(u2 - 512) * 8));
            ar3 = *(const short8*)((u3 < 512 ? whi + wb + (size_t)u3 * 8
                                             : wlo + wb + (size_t)(u3 - 512) * 8));
        }
        asm volatile("s_waitcnt lgkmcnt(0)" ::: "memory");
        __builtin_amdgcn_s_barrier();
        __builtin_amdgcn_sched_barrier(0);

        for (int ch = 0; ch < NCH; ++ch) {
            __builtin_amdgcn_s_setprio(1);
            // A fragments for this wave's m-tiles, read ONCE per chunk
            short8 ahv[MTW], alv[MTW];
#pragma unroll
            for (int mt2 = 0; mt2 < MTW; ++mt2) {
                const int au = ((m0 + mt2) * 64 + lane) * 8;
                ahv[mt2] = *(const short8*)&Abuf[au];
                alv[mt2] = *(const short8*)&Abuf[4096 + au];
            }
#pragma unroll
            for (int pt = 0; pt < NPT; ++pt) {
                const int boff = (pt * 16 + mrow) * KS + kq * 8;
                const short8 bh = *(const short8*)&Shi[boff];
                const short8 bl = *(const short8*)&Slo[boff];
#pragma unroll
                for (int mt2 = 0; mt2 < MTW; ++mt2) {
                    f32x4 a = acc[mt2 * NPT + pt];
                    a = __builtin_amdgcn_mfma_f32_16x16x32_bf16(alv[mt2], bh, a, 0, 0, 0);
                    a = __builtin_amdgcn_mfma_f32_16x16x32_bf16(ahv[mt2], bl, a, 0, 0, 0);
                    a = __builtin_amdgcn_mfma_f32_16x16x32_bf16(ahv[mt2], bh, a, 0, 0, 0);
                    acc[mt2 * NPT + pt] = a;
                }
            }
            __builtin_amdgcn_s_setprio(0);
            if (ch + 1 < NCH) {
                asm volatile("s_waitcnt lgkmcnt(0)" ::: "memory");
                __builtin_amdgcn_s_barrier();
                __builtin_amdgcn_sched_barrier(0);
                // ---- write phase: ds_write A(ch+1) from regs (loads landed),
                //      finish gathers -> S, issue next gathers + next A ----
                {
                    const int u0 = tid, u1 = tid + NT;
                    const int u2 = tid + 2 * NT, u3 = tid + 3 * NT;
                    *(short8*)&Abuf[(size_t)u0 * 8] = ar0;
                    *(short8*)&Abuf[(size_t)u1 * 8] = ar1;
                    *(short8*)&Abuf[(size_t)u2 * 8] = ar2;
                    *(short8*)&Abuf[(size_t)u3 * 8] = ar3;
                }
                sample_finish<CIN, HH, WW, POS, KS>(ewt, v0, v1, Shi, Slo,
                                                    tt, (ch + 1) * KC);
                if (ch + 2 < NCH) {
                    sample_issue<CIN, HH, WW, POS>(xb, eoff2, v0, v1, tt,
                                                   (ch + 2) * KC);
                    const size_t wb = (size_t)(ch + 2) * 4096;
                    const int u0 = tid, u1 = tid + NT;
                    const int u2 = tid + 2 * NT, u3 = tid + 3 * NT;
                    ar0 = *(const short8*)((u0 < 512 ? whi + wb + (size_t)u0 * 8
                                                     : wlo + wb + (size_t)(u0 - 512) * 8));
                    ar1 = *(const short8*)((u1 < 512 ? whi + wb + (size_t)u1 * 8
                                                     : wlo + wb + (size_t)(u1 - 512) * 8));
                    ar2 = *(const short8*)((u2 < 512 ? whi + wb + (size_t)u2 * 8
                                                     : wlo + wb + (size_t)(u2 - 512) * 8));
                    ar3 = *(const short8*)((u3 < 512 ? whi + wb + (size_t)u3 * 8
                                                     : wlo + wb + (size_t)(u3 - 512) * 8));
                }
                asm volatile("s_waitcnt lgkmcnt(0)" ::: "memory");
                __builtin_amdgcn_s_barrier();
                __builtin_amdgcn_sched_barrier(0);
            }
        }
    } else {
        ushort* S00 = Sbase + kgid * (4 * SBUF);
        sample_chunk<CIN, HH, WW, POS, KS>(xb, eoff2, ewt, S00, S00 + SBUF,
                                           tt, kgid * NCH * KC);
        __syncthreads();

        for (int ch = 0; ch < NCH; ++ch) {
            const int cur = ch & 1;
            ushort* Sc = S00 + (cur * 2) * SBUF;
            // B fragments for all pos-tiles (held across the sampler)
            short8 bhv[NPT], blv[NPT];
#pragma unroll
            for (int pt = 0; pt < NPT; ++pt) {
                const int boff = (pt * 16 + mrow) * KS + kq * 8;
                bhv[pt] = *(const short8*)&Sc[boff];
                blv[pt] = *(const short8*)&Sc[SBUF + boff];
            }
            if (ch + 1 < NCH) {
                ushort* Sn = S00 + ((cur ^ 1) * 2) * SBUF;
                sample_chunk<CIN, HH, WW, POS, KS>(xb, eoff2, ewt,
                                                   Sn, Sn + SBUF, tt,
                                                   (kgid * NCH + ch + 1) * KC);
            }
            // A fragments just-in-time from global (fragment order, coalesced)
            const size_t abase = (size_t)((kgid * NCH + ch) * 8) * 512;
            __builtin_amdgcn_s_setprio(1);
#pragma unroll
            for (int mt2 = 0; mt2 < MTW; ++mt2) {
                const size_t ao = abase + (size_t)(((m0 + mt2) * 64 + lane) * 8);
                const short8 ah = *(const short8*)(whi + ao);
                const short8 al = *(const short8*)(wlo + ao);
#pragma unroll
                for (int pt = 0; pt < NPT; ++pt) {
                    f32x4 a = acc[mt2 * NPT + pt];
                    a = __builtin_amdgcn_mfma_f32_16x16x32_bf16(al, bhv[pt], a, 0, 0, 0);
                    a = __builtin_amdgcn_mfma_f32_16x16x32_bf16(ah, blv[pt], a, 0, 0, 0);
                    a = __builtin_amdgcn_mfma_f32_16x16x32_bf16(ah, bhv[pt], a, 0, 0, 0);
                    acc[mt2 * NPT + pt] = a;
                }
            }
            __builtin_amdgcn_s_setprio(0);
            __syncthreads();
        }
    }

    constexpr int RS = POS + 1;
    constexpr int SL = 128 * RS;
    float* red = (float*)Sbase;

    if constexpr (KWAVES == 4) {
        if (kgid >= 2) {
#pragma unroll
            for (int mt2 = 0; mt2 < MTW; ++mt2)
#pragma unroll
                for (int pt = 0; pt < NPT; ++pt)
#pragma unroll
                    for (int r = 0; r < 4; ++r) {
                        const int co = (m0 + mt2) * 16 + kq * 4 + r;
                        red[(kgid - 2) * SL + co * RS + pt * 16 + mrow] =
                            acc[mt2 * NPT + pt][r];
                    }
        }
        __syncthreads();
        if (kgid < 2) {
#pragma unroll
            for (int mt2 = 0; mt2 < MTW; ++mt2)
#pragma unroll
                for (int pt = 0; pt < NPT; ++pt)
#pragma unroll
                    for (int r = 0; r < 4; ++r) {
                        const int co = (m0 + mt2) * 16 + kq * 4 + r;
                        acc[mt2 * NPT + pt][r] +=
                            red[kgid * SL + co * RS + pt * 16 + mrow];
                    }
        }
        __syncthreads();
        if (kgid == 1) {
#pragma unroll
            for (int mt2 = 0; mt2 < MTW; ++mt2)
#pragma unroll
                for (int pt = 0; pt < NPT; ++pt)
#pragma unroll
                    for (int r = 0; r < 4; ++r) {
                        const int co = (m0 + mt2) * 16 + kq * 4 + r;
                        red[co * RS + pt * 16 + mrow] = acc[mt2 * NPT + pt][r];
                    }
        }
        __syncthreads();
        if (kgid == 0) {
#pragma unroll
            for (int mt2 = 0; mt2 < MTW; ++mt2)
#pragma unroll
                for (int pt = 0; pt < NPT; ++pt)
#pragma unroll
                    for (int r = 0; r < 4; ++r) {
                        const int co = (m0 + mt2) * 16 + kq * 4 + r;
                        acc[mt2 * NPT + pt][r] += red[co * RS + pt * 16 + mrow];
                    }
        }
    } else if constexpr (KWAVES == 2) {
        if (kgid == 1) {
#pragma unroll
            for (int mt2 = 0; mt2 < MTW; ++mt2)
#pragma unroll
                for (int pt = 0; pt < NPT; ++pt)
#pragma unroll
                    for (int r = 0; r < 4; ++r) {
                        const int co = (m0 + mt2) * 16 + kq * 4 + r;
                        red[co * RS + pt * 16 + mrow] = acc[mt2 * NPT + pt][r];
                    }
        }
        __syncthreads();
        if (kgid == 0) {
#pragma unroll
            for (int mt2 = 0; mt2 < MTW; ++mt2)
#pragma unroll
                for (int pt = 0; pt < NPT; ++pt)
#pragma unroll
                    for (int r = 0; r < 4; ++r) {
                        const int co = (m0 + mt2) * 16 + kq * 4 + r;
                        acc[mt2 * NPT + pt][r] += red[co * RS + pt * 16 + mrow];
                    }
        }
    }

    if (kgid == 0) {
        float* outb = out + (size_t)b * 128 * HW + p0;
#pragma unroll
        for (int mt2 = 0; mt2 < MTW; ++mt2)
#pragma unroll
            for (int pt = 0; pt < NPT; ++pt)
#pragma unroll
                for (int r = 0; r < 4; ++r) {
                    const int co = (m0 + mt2) * 16 + kq * 4 + r;
                    outb[(size_t)co * HW + pt * 16 + mrow] =
                        fmaxf(acc[mt2 * NPT + pt][r] * invp[co] + shp[co], 0.f);
                }
    }
}

// ---------------- depthwise transposed-conv upsample x2 (k=4, pad 2) --------
__global__ __launch_bounds__(256) void upsample_kernel(
    const float* __restrict__ y,    // (4,128,64,64)
    const float* __restrict__ wup,  // (128,1,4,4)
    float* __restrict__ out)        // (4,128,128,128)
{
    const int idx = blockIdx.x * 256 + threadIdx.x;
    const int ox = idx & 127;
    const int oy = (idx >> 7) & 127;
    const int c  = (idx >> 14) & 127;
    const int b  = idx >> 21;

    const float* yc = y + (size_t)(b * 128 + c) * 4096;
    const float* wc = wup + c * 16;

    float acc = 0.f;
#pragma unroll
    for (int ky = 0; ky < 4; ++ky) {
        const int qy = oy + ky - 2;
        if (qy & 1) continue;
        const int iy = qy >> 1;
        if (iy < 0 || iy >= 64) continue;
#pragma unroll
        for (int kx = 0; kx < 4; ++kx) {
            const int qx = ox + kx - 2;
            if (qx & 1) continue;
            const int ix = qx >> 1;
            if (ix < 0 || ix >= 64) continue;
            acc += yc[iy * 64 + ix] * wc[(3 - ky) * 4 + (3 - kx)];
        }
    }
    out[idx] = acc;
}

// ---------------------------------------------------------------------------
extern "C" void kernel_launch(void* const* d_in, const int* in_sizes, int n_in,
                              void* d_out, int out_size, void* d_ws, size_t ws_size,
                              hipStream_t stream) {
    const float* x      = (const float*)d_in[0];
    const float* w_off1 = (const float*)d_in[1];
    const float* b_off1 = (const float*)d_in[2];
    const float* w1     = (const float*)d_in[3];
    const float* b1     = (const float*)d_in[4];
    const float* g1v    = (const float*)d_in[5];
    const float* be1    = (const float*)d_in[6];
    const float* m1     = (const float*)d_in[7];
    const float* v1     = (const float*)d_in[8];
    const float* w_up   = (const float*)d_in[9];
    const float* w_off2 = (const float*)d_in[10];
    const float* b_off2 = (const float*)d_in[11];
    const float* w2     = (const float*)d_in[12];
    const float* b2     = (const float*)d_in[13];
    const float* g2v    = (const float*)d_in[14];
    const float* be2    = (const float*)d_in[15];
    const float* m2     = (const float*)d_in[16];
    const float* v2     = (const float*)d_in[17];

    float* ws  = (float*)d_ws;
    float* om1 = ws;                     // 4*27*4096   =   442368 f
    float* y1  = om1 + 442368;           // 4*128*4096  =  2097152 f
    float* up  = y1 + 2097152;           // 4*128*16384 =  8388608 f
    float* om2 = up + 8388608;           // 4*27*16384  =  1769472 f
    float* outf = (float*)d_out;

    // `up` region (dead until upsample writes it): w1 + w_off1 splits
    ushort* w1hi  = (ushort*)up;         // 294912
    ushort* w1lo  = w1hi + 294912;       // 294912
    ushort* wo1hi = w1lo + 294912;       // 32*2304 = 73728
    ushort* wo1lo = wo1hi + 73728;       // 73728
    // `y1` region (dead after upsample reads it): w2 + w_off2 splits
    ushort* w2hi  = (ushort*)y1;         // 147456
    ushort* w2lo  = w2hi + 147456;       // 147456
    ushort* wo2hi = w2lo + 147456;       // 32*1152 = 36864
    ushort* wo2lo = wo2hi + 36864;       // 36864

    // prep: w1 (dcn1) + w_off1 (conv1) splits, fragment order
    wsplit_perm_kernel<<<(294912 + 255) / 256, 256, 0, stream>>>(
        w1, w1hi, w1lo, 256, 294912);
    wsplit_perm_conv_kernel<<<(73728 + 255) / 256, 256, 0, stream>>>(
        w_off1, wo1hi, wo1lo, 256, 73728);

    // om1 = conv3x3(x, w_off1) + b_off1 — MFMA, POS=16, KWAVES=4
    conv_mfma_kernel<256, 64, 64, 16, 4, 4>
        <<<1024, 256, 21632, stream>>>(x, wo1hi, wo1lo, b_off1, om1);

    // y1 = bn_relu(dcn1) — MFMA, POS=32, 4-way K-split, M-split waves
    dcn_mfma_kernel<256, 64, 64, 32, 4, 4, false, false>
        <<<4 * (4096 / 32), 512, 47744, stream>>>(
        x, om1, om1, w1hi, w1lo, b1, g1v, be1, m1, v1, y1);
    // up = depthwise transposed upsample (clobbers w1/wo1 splits — now dead)
    upsample_kernel<<<8388608 / 256, 256, 0, stream>>>(y1, w_up, up);

    // prep: w2 (dcn2) + w_off2 (conv2) splits (y1 now dead)
    wsplit_perm_kernel<<<(147456 + 255) / 256, 256, 0, stream>>>(
        w2, w2hi, w2lo, 128, 147456);
    wsplit_perm_conv_kernel<<<(36864 + 255) / 256, 256, 0, stream>>>(
        w_off2, wo2hi, wo2lo, 128, 36864);

    // om2 = conv3x3(up, w_off2) + b_off2 — MFMA, POS=64, KWAVES=1
    conv_mfma_kernel<128, 128, 128, 64, 1, 4>
        <<<1024, 256, 25088, stream>>>(up, wo2hi, wo2lo, b_off2, om2);

    // out = bn_relu(dcn2) — MFMA, POS=64, A-staged (split), single-S, M-split
    dcn_mfma_kernel<128, 128, 128, 64, 1, 4, true, false>
        <<<4 * (16384 / 64), 256, 39168, stream>>>(
        up, om2, om2, w2hi, w2lo, b2, g2v, be2, m2, v2, outf);
}

// Round 21
// 352.637 us; speedup vs baseline: 1.0408x; 1.0196x over previous
//
#include <hip/hip_runtime.h>
#include <hip/hip_bf16.h>
#include <cmath>

// ---------------------------------------------------------------------------
// Pipeline: y1 = bn_relu(dcn(x, w_off1, b_off1, w1, b1))        (4,128,64,64)
//           up = up_depthwise(y1, w_up, f=2)                    (4,128,128,128)
//           out = bn_relu(dcn(up, w_off2, b_off2, w2, b2))      (4,128,128,128)
// ALL GEMM-shaped work on mfma_f32_16x16x32_bf16, split-bf16 (hi/lo, 3 prod).
// R21: upsample vectorized — 4 consecutive ox outputs/thread (ox0 % 4 == 0
//      so tap parity constant-folds; wave divergence eliminated), float4
//      store. Per-output accumulation order unchanged (bit-identical).
// dcn2 (R15 config, settled): A-stage T14-split, M-split waves, single-S
// alternating phases. Depth-2 gathers DEAD (R16 spill / R19 fail).
// conv_off -> conv_mfma (M=27 padded to 32, tap-sampler B).
// Weights pre-permuted into per-chunk fragment order (coalesced A loads).
// Workspace: om1 | y1 | up | om2 ; w1+wo1 splits parked in `up`,
// w2+wo2 splits parked in `y1`.
// ---------------------------------------------------------------------------

#define EPSV 1e-5f

typedef __attribute__((ext_vector_type(8))) short short8;
typedef __attribute__((ext_vector_type(4))) float f32x4;

__device__ __forceinline__ ushort f2bf(float f) {
    union { float f; uint u; } v; v.f = f;
    const uint r = v.u + 0x7fffu + ((v.u >> 16) & 1u);   // RNE
    return (ushort)(r >> 16);
}
__device__ __forceinline__ float bf2f(ushort h) {
    union { uint u; float f; } v; v.u = ((uint)h) << 16;
    return v.f;
}
__device__ __forceinline__ float2 ld2u(const float* p) {
    float2 v; __builtin_memcpy(&v, p, sizeof(float2)); return v;
}
// packed bf16 RNE convert: dst.lo = bf16(a), dst.hi = bf16(b)
__device__ __forceinline__ uint cvtpk_bf16(float a, float b) {
    uint r;
    asm("v_cvt_pk_bf16_f32 %0, %1, %2" : "=v"(r) : "v"(a), "v"(b));
    return r;
}

// ---- pack 8 fp32 -> bf16 hi/lo rows of S (cvt_pk fast path) ----------------
template <int KS>
__device__ __forceinline__ void pack_store8(
    const float* s, ushort* __restrict__ Shi, ushort* __restrict__ Slo,
    int pp, int j0)
{
    uint hw[4], lw[4];
#pragma unroll
    for (int q = 0; q < 4; ++q) {
        const float s0 = s[2 * q], s1 = s[2 * q + 1];
        const uint h = cvtpk_bf16(s0, s1);
        union { uint u; float f; } h0, h1;
        h0.u = h << 16;
        h1.u = h & 0xffff0000u;
        hw[q] = h;
        lw[q] = cvtpk_bf16(s0 - h0.f, s1 - h1.f);
    }
    uint4 hv; hv.x = hw[0]; hv.y = hw[1]; hv.z = hw[2]; hv.w = hw[3];
    uint4 lv; lv.x = lw[0]; lv.y = lw[1]; lv.z = lw[2]; lv.w = lw[3];
    *(uint4*)&Shi[pp * KS + j0] = hv;
    *(uint4*)&Slo[pp * KS + j0] = lv;
}

// ------- weight split: fp32 -> bf16 hi/lo in per-chunk FRAGMENT order -------
__global__ __launch_bounds__(256) void wsplit_perm_kernel(
    const float* __restrict__ w, ushort* __restrict__ hi,
    ushort* __restrict__ lo, int cin, int n)
{
    const int i = blockIdx.x * 256 + threadIdx.x;
    if (i >= n) return;
    const int cin9 = cin * 9;
    const int co = i / cin9;
    const int k  = i - co * cin9;            // channel-major K index
    const int ch = k >> 5;
    const int kq = (k & 31) >> 3;
    const int j  = k & 7;
    const int mt = co >> 4;
    const int lane = (co & 15) | (kq << 4);
    const size_t dst = ((size_t)(ch * 8 + mt) * 64 + lane) * 8 + j;
    const float f = w[i];
    const ushort h = f2bf(f);
    hi[dst] = h;
    lo[dst] = f2bf(f - bf2f(h));
}

// ------- conv weight split: (27,CIN,3,3) -> M=32 zero-padded frag order -----
__global__ __launch_bounds__(256) void wsplit_perm_conv_kernel(
    const float* __restrict__ w, ushort* __restrict__ hi,
    ushort* __restrict__ lo, int cin, int n)   // n = 32*cin*9
{
    const int i = blockIdx.x * 256 + threadIdx.x;
    if (i >= n) return;
    const int cin9 = cin * 9;
    const int co = i / cin9;
    const int k  = i - co * cin9;
    const int ch = k >> 5;
    const int kq = (k & 31) >> 3;
    const int j  = k & 7;
    const int mt = co >> 4;
    const int lane = (co & 15) | (kq << 4);
    const size_t dst = ((size_t)(ch * 2 + mt) * 64 + lane) * 8 + j;
    const float f = (co < 27) ? w[(size_t)co * cin9 + k] : 0.f;
    const ushort h = f2bf(f);
    hi[dst] = h;
    lo[dst] = f2bf(f - bf2f(h));
}

// ---------------- offset conv on MFMA: 3x3, pad 1, 27(->32) outputs ---------
template <int CIN, int HH, int WW, int POS, int KS>
__device__ __forceinline__ void conv_sample_chunk(
    const float* __restrict__ xb, const uint* __restrict__ toff,
    const float* __restrict__ twt, ushort* __restrict__ Shi,
    ushort* __restrict__ Slo, int tt, int kbase)
{
    constexpr int HW = HH * WW;
    const int pp = tt & (POS - 1);
    const int j0 = (tt / POS) * 8;
    float s[8];
#pragma unroll
    for (int j = 0; j < 8; ++j) {
        const int kg = kbase + j0 + j;
        const int c  = (kg * 7282) >> 16;       // /9 (exact for kg<2304)
        const int k9 = kg - c * 9;
        const int ei = k9 * POS + pp;
        s[j] = xb[(size_t)c * HW + toff[ei]] * twt[ei];
    }
    pack_store8<KS>(s, Shi, Slo, pp, j0);
}

template <int CIN, int HH, int WW, int POS, int KWAVES, int MINW>
__global__ __launch_bounds__((POS / 16) * KWAVES * 64, MINW) void conv_mfma_kernel(
    const float* __restrict__ in,    // (B, CIN, HH, WW)
    const ushort* __restrict__ whi,  // (32, CIN*9) frag order, zero-padded
    const ushort* __restrict__ wlo,
    const float* __restrict__ bias,  // (27)
    float* __restrict__ om)          // (B, 27, HH*WW)
{
    constexpr int HW   = HH * WW;
    constexpr int K    = CIN * 9;
    constexpr int NPQ  = POS / 16;
    constexpr int NT   = NPQ * KWAVES * 64;
    constexpr int KC   = 32;
    constexpr int KS   = 40;
    constexpr int NCHT = K / KC;
    constexpr int NCH  = NCHT / KWAVES;
    constexpr int SBUF = POS * KS;

    extern __shared__ __align__(16) char smem[];
    uint*   toff  = (uint*)smem;              // 9*POS
    float*  twt   = (float*)(toff + 9 * POS); // 9*POS
    ushort* Sbase = (ushort*)(twt + 9 * POS);

    const int tid = threadIdx.x;
    const int nt  = HW / POS;
    const int cpx = gridDim.x >> 3;
    const int bid = (blockIdx.x & 7) * cpx + (blockIdx.x >> 3);
    const int b   = bid / nt;
    const int p0  = (bid - b * nt) * POS;

    for (int i = tid; i < 9 * POS; i += NT) {
        const int k9 = i / POS, pp = i - k9 * POS;
        const int p  = p0 + pp;
        const int yy = p / WW, xx = p - yy * WW;
        const int ky = (k9 * 11) >> 5, kx = k9 - ky * 3;
        const int iy = yy + ky - 1, ix = xx + kx - 1;
        const bool v = (iy >= 0) && (iy < HH) && (ix >= 0) && (ix < WW);
        const int cy = min(max(iy, 0), HH - 1);
        const int cx = min(max(ix, 0), WW - 1);
        toff[i] = (uint)(cy * WW + cx);
        twt[i]  = v ? 1.f : 0.f;
    }
    __syncthreads();

    const float* xb = in + (size_t)b * CIN * HW;
    const int lane = tid & 63;
    const int w    = tid >> 6;
    const int wq   = w & (NPQ - 1);
    const int kgid = w / NPQ;
    const int tt   = tid & (NPQ * 64 - 1);
    ushort* S00 = Sbase + kgid * (4 * SBUF);

    f32x4 acc[2];
    acc[0] = (f32x4){0.f, 0.f, 0.f, 0.f};
    acc[1] = (f32x4){0.f, 0.f, 0.f, 0.f};
    const int mrow = lane & 15;
    const int kq   = lane >> 4;

    conv_sample_chunk<CIN, HH, WW, POS, KS>(xb, toff, twt, S00, S00 + SBUF,
                                            tt, kgid * NCH * KC);
    __syncthreads();

    for (int ch = 0; ch < NCH; ++ch) {
        const int cur = ch & 1;
        ushort* Sc = S00 + (cur * 2) * SBUF;
        const int boff = (wq * 16 + mrow) * KS + kq * 8;
        const short8 bh = *(const short8*)&Sc[boff];
        const short8 bl = *(const short8*)&Sc[SBUF + boff];
        if (ch + 1 < NCH) {
            ushort* Sn = S00 + ((cur ^ 1) * 2) * SBUF;
            conv_sample_chunk<CIN, HH, WW, POS, KS>(xb, toff, twt,
                                                    Sn, Sn + SBUF, tt,
                                                    (kgid * NCH + ch + 1) * KC);
        }
        const size_t abase = (size_t)((kgid * NCH + ch) * 2) * 512;
        __builtin_amdgcn_s_setprio(1);
#pragma unroll
        for (int mt = 0; mt < 2; ++mt) {
            const size_t ao = abase + (size_t)((mt * 64 + lane) * 8);
            const short8 ah = *(const short8*)(whi + ao);
            const short8 al = *(const short8*)(wlo + ao);
            acc[mt] = __builtin_amdgcn_mfma_f32_16x16x32_bf16(al, bh, acc[mt], 0, 0, 0);
            acc[mt] = __builtin_amdgcn_mfma_f32_16x16x32_bf16(ah, bl, acc[mt], 0, 0, 0);
            acc[mt] = __builtin_amdgcn_mfma_f32_16x16x32_bf16(ah, bh, acc[mt], 0, 0, 0);
        }
        __builtin_amdgcn_s_setprio(0);
        __syncthreads();
    }

    const int pcolb = wq * 16 + mrow;
    constexpr int RS = POS + 1;
    constexpr int SL = 32 * RS;
    float* red = (float*)Sbase;

    if constexpr (KWAVES == 4) {
        if (kgid >= 2) {
#pragma unroll
            for (int mt = 0; mt < 2; ++mt)
#pragma unroll
                for (int r = 0; r < 4; ++r) {
                    const int co = mt * 16 + kq * 4 + r;
                    red[(kgid - 2) * SL + co * RS + pcolb] = acc[mt][r];
                }
        }
        __syncthreads();
        if (kgid < 2) {
#pragma unroll
            for (int mt = 0; mt < 2; ++mt)
#pragma unroll
                for (int r = 0; r < 4; ++r) {
                    const int co = mt * 16 + kq * 4 + r;
                    acc[mt][r] += red[kgid * SL + co * RS + pcolb];
                }
        }
        __syncthreads();
        if (kgid == 1) {
#pragma unroll
            for (int mt = 0; mt < 2; ++mt)
#pragma unroll
                for (int r = 0; r < 4; ++r) {
                    const int co = mt * 16 + kq * 4 + r;
                    red[co * RS + pcolb] = acc[mt][r];
                }
        }
        __syncthreads();
        if (kgid == 0) {
#pragma unroll
            for (int mt = 0; mt < 2; ++mt)
#pragma unroll
                for (int r = 0; r < 4; ++r) {
                    const int co = mt * 16 + kq * 4 + r;
                    acc[mt][r] += red[co * RS + pcolb];
                }
        }
    } else if constexpr (KWAVES == 2) {
        if (kgid == 1) {
#pragma unroll
            for (int mt = 0; mt < 2; ++mt)
#pragma unroll
                for (int r = 0; r < 4; ++r) {
                    const int co = mt * 16 + kq * 4 + r;
                    red[co * RS + pcolb] = acc[mt][r];
                }
        }
        __syncthreads();
        if (kgid == 0) {
#pragma unroll
            for (int mt = 0; mt < 2; ++mt)
#pragma unroll
                for (int r = 0; r < 4; ++r) {
                    const int co = mt * 16 + kq * 4 + r;
                    acc[mt][r] += red[co * RS + pcolb];
                }
        }
    }

    if (kgid == 0) {
        float* ob = om + (size_t)b * 27 * HW + p0 + pcolb;
#pragma unroll
        for (int mt = 0; mt < 2; ++mt)
#pragma unroll
            for (int r = 0; r < 4; ++r) {
                const int co = mt * 16 + kq * 4 + r;
                if (co < 27)
                    ob[(size_t)co * HW] = acc[mt][r] + bias[co];
            }
    }
}

// ---------------- paired sampler: issue / finish ----------------------------
template <int CIN, int HH, int WW, int POS>
__device__ __forceinline__ void sample_issue(
    const float* __restrict__ xb, const uint* __restrict__ eoff2,
    float2* v0, float2* v1, int tt, int kbase)
{
    constexpr int HW = HH * WW;
    const int pp = tt & (POS - 1);
    const int j0 = (tt / POS) * 8;
#pragma unroll
    for (int j = 0; j < 8; ++j) {
        const int kg = kbase + j0 + j;
        const int c  = (kg * 7282) >> 16;       // /9 (exact for kg<2304)
        const int k9 = kg - c * 9;
        const uint e = eoff2[k9 * POS + pp];
        const float* chp = xb + (size_t)c * HW;
        v0[j] = ld2u(chp + (e & 0xffffu));
        v1[j] = ld2u(chp + (e >> 16));
    }
}

template <int CIN, int HH, int WW, int POS, int KS>
__device__ __forceinline__ void sample_finish(
    const float4* __restrict__ ewt, const float2* v0, const float2* v1,
    ushort* __restrict__ Shi, ushort* __restrict__ Slo, int tt, int kbase)
{
    const int pp = tt & (POS - 1);
    const int j0 = (tt / POS) * 8;
    float s[8];
#pragma unroll
    for (int j = 0; j < 8; ++j) {
        const int kg = kbase + j0 + j;
        const int c  = (kg * 7282) >> 16;
        const int k9 = kg - c * 9;
        const float4 wv = ewt[k9 * POS + pp];
        s[j] = v0[j].x * wv.x + v0[j].y * wv.y
             + v1[j].x * wv.z + v1[j].y * wv.w;
    }
    pack_store8<KS>(s, Shi, Slo, pp, j0);
}

template <int CIN, int HH, int WW, int POS, int KS>
__device__ __forceinline__ void sample_chunk(
    const float* __restrict__ xb, const uint* __restrict__ eoff2,
    const float4* __restrict__ ewt, ushort* __restrict__ Shi,
    ushort* __restrict__ Slo, int tt, int kbase)
{
    float2 v0[8], v1[8];
    sample_issue<CIN, HH, WW, POS>(xb, eoff2, v0, v1, tt, kbase);
    sample_finish<CIN, HH, WW, POS, KS>(ewt, v0, v1, Shi, Slo, tt, kbase);
}

// ---------------- fused DCN on MFMA: sample + GEMM + bias + BN + ReLU -------
// M-SPLIT: wave wm owns MTW = 8/NPQ m-tiles x all POS positions (NPT tiles).
template <int CIN, int HH, int WW, int POS, int KWAVES, int MINW,
          bool ASTAGE, bool OMS>
__global__ __launch_bounds__((POS / 16) * KWAVES * 64, MINW) void dcn_mfma_kernel(
    const float* __restrict__ xin,   // (B, CIN, HH, WW)
    const float* __restrict__ om,    // (B, 27, HH, WW)
    const float* __restrict__ omB,   // partial (OMS only)
    const ushort* __restrict__ whi,  // (128, K) bf16 hi, fragment order
    const ushort* __restrict__ wlo,  // (128, K) bf16 lo, fragment order
    const float* __restrict__ bias,
    const float* __restrict__ gam, const float* __restrict__ bet,
    const float* __restrict__ mu,  const float* __restrict__ var,
    float* __restrict__ out)         // (B, 128, HH*WW)
{
    constexpr int HW   = HH * WW;
    constexpr int K    = CIN * 9;
    constexpr int NPQ  = POS / 16;
    constexpr int NT   = NPQ * KWAVES * 64;
    constexpr int KC   = 32;
    constexpr int KS   = 40;
    constexpr int NCHT = K / KC;
    constexpr int NCH  = NCHT / KWAVES;
    constexpr int SBUF = POS * KS;
    constexpr int ABN  = ASTAGE ? 8192 : 0;
    constexpr int MTW  = 8 / NPQ;             // m-tiles per wave
    constexpr int NPT  = POS / 16;            // pos-tiles per wave

    extern __shared__ __align__(16) char smem[];
    uint*    eoff2 = (uint*)smem;
    float4*  ewt   = (float4*)(eoff2 + 9 * POS);
    float*   invp  = (float*)(ewt + 9 * POS);
    float*   shp   = invp + 128;
    ushort*  Abuf  = (ushort*)(shp + 128);
    ushort*  Sbase = Abuf + ABN;

    const int tid = threadIdx.x;
    const int nt  = HW / POS;
    const int cpx = gridDim.x >> 3;
    const int bid = (blockIdx.x & 7) * cpx + (blockIdx.x >> 3);
    const int b   = bid / nt;
    const int p0  = (bid - b * nt) * POS;

    const float* omb  = om + (size_t)b * 27 * HW;
    const float* ombB = OMS ? (omB + (size_t)b * 27 * HW) : nullptr;
    for (int i = tid; i < 9 * POS; i += NT) {
        const int k9 = i / POS, pp = i - k9 * POS;
        const int p  = p0 + pp;
        const int yy = p / WW;
        const int xx = p - yy * WW;
        float oy = omb[(size_t)k9 * HW + p];
        float ox = omb[(size_t)(9 + k9) * HW + p];
        float mv = omb[(size_t)(18 + k9) * HW + p];
        if constexpr (OMS) {
            oy += ombB[(size_t)k9 * HW + p];
            ox += ombB[(size_t)(9 + k9) * HW + p];
            mv += ombB[(size_t)(18 + k9) * HW + p];
        }
        const float m  = 1.0f / (1.0f + expf(-mv));
        const int ky = (k9 * 11) >> 5;
        const int kx = k9 - ky * 3;
        const float py = (float)(yy + ky - 1) + oy;
        const float px = (float)(xx + kx - 1) + ox;
        const float y0f = floorf(py), x0f = floorf(px);
        const int   y0  = (int)y0f,  x0 = (int)x0f;
        const int by0 = min(max(y0, 0), HH - 1);
        const int by1 = min(max(y0 + 1, 0), HH - 1);
        const int bx  = min(max(x0, 0), WW - 2);
        const float wy1 = py - y0f, wx1 = px - x0f;
        const float fy0 = (y0 >= 0  && y0 < HH)     ? (1.f - wy1) * m : 0.f;
        const float fy1 = (y0 >= -1 && y0 < HH - 1) ? wy1 * m         : 0.f;
        const float fx0v = 1.f - wx1, fx1v = wx1;
        float gx0 = 0.f, gx1 = 0.f;
        if (x0 >= 0 && x0 < WW)         { if (x0 == bx)     gx0 += fx0v; else gx1 += fx0v; }
        if (x0 + 1 >= 0 && x0 + 1 < WW) { if (x0 + 1 == bx) gx0 += fx1v; else gx1 += fx1v; }
        eoff2[i] = (uint)(by0 * WW + bx) | ((uint)(by1 * WW + bx) << 16);
        float4 wv; wv.x = fy0 * gx0; wv.y = fy0 * gx1;
                   wv.z = fy1 * gx0; wv.w = fy1 * gx1;
        ewt[i] = wv;
    }
    for (int i = tid; i < 128; i += NT) {
        const float iv = gam[i] * rsqrtf(var[i] + EPSV);
        invp[i] = iv;
        shp[i]  = bet[i] - mu[i] * iv + bias[i] * iv;
    }
    __syncthreads();

    const float* xb   = xin + (size_t)b * CIN * HW;
    const int lane = tid & 63;
    const int w    = tid >> 6;
    const int wm   = w & (NPQ - 1);          // m-group of this wave
    const int kgid = w / NPQ;
    const int tt   = tid & (NPQ * 64 - 1);
    const int m0   = wm * MTW;

    f32x4 acc[8];                             // [mt2][pt] flattened
#pragma unroll
    for (int mt = 0; mt < 8; ++mt) acc[mt] = (f32x4){0.f, 0.f, 0.f, 0.f};

    const int mrow = lane & 15;
    const int kq   = lane >> 4;

    if constexpr (ASTAGE) {
        // ===== single-S-buffer alternating-phase pipeline (A also split) ====
        ushort* Shi = Sbase;
        ushort* Slo = Sbase + SBUF;
        float2 v0[8], v1[8];
        short8 ar0, ar1, ar2, ar3;            // A-stage regs for ch+1
        sample_chunk<CIN, HH, WW, POS, KS>(xb, eoff2, ewt, Shi, Slo, tt, 0);
        {   // stage A(0) directly (once; latency exposed only here)
#pragma unroll
            for (int t = 0; t < 1024 / NT; ++t) {
                const int u = tid + t * NT;
                const ushort* srcp = (u < 512)
                    ? (whi + (size_t)u * 8)
                    : (wlo + (size_t)(u - 512) * 8);
                *(short8*)&Abuf[(size_t)u * 8] = *(const short8*)srcp;
            }
        }
        if (NCH > 1) {
            sample_issue<CIN, HH, WW, POS>(xb, eoff2, v0, v1, tt, KC);
            // issue A-loads(1) into regs (land during MFMA phase)
            const size_t wb = (size_t)1 * 4096;
            const int u0 = tid, u1 = tid + NT, u2 = tid + 2 * NT, u3 = tid + 3 * NT;
            ar0 = *(const short8*)((u0 < 512 ? whi + wb + (size_t)u0 * 8
                                             : wlo + wb + (size_t)(u0 - 512) * 8));
            ar1 = *(const short8*)((u1 < 512 ? whi + wb + (size_t)u1 * 8
                                             : wlo + wb + (size_t)(u1 - 512) * 8));
            ar2 = *(const short8*)((u2 < 512 ? whi + wb + (size_t)u2 * 8
                                             : wlo + wb + (size_t)(u2 - 512) * 8));
            ar3 = *(const short8*)((u3 < 512 ? whi + wb + (size_t)u3 * 8
                                             : wlo + wb + (size_t)(u3 - 512) * 8));
        }
        asm volatile("s_waitcnt lgkmcnt(0)" ::: "memory");
        __builtin_amdgcn_s_barrier();
        __builtin_amdgcn_sched_barrier(0);

        for (int ch = 0; ch < NCH; ++ch) {
            __builtin_amdgcn_s_setprio(1);
            // A fragments for this wave's m-tiles, read ONCE per chunk
            short8 ahv[MTW], alv[MTW];
#pragma unroll
            for (int mt2 = 0; mt2 < MTW; ++mt2) {
                const int au = ((m0 + mt2) * 64 + lane) * 8;
                ahv[mt2] = *(const short8*)&Abuf[au];
                alv[mt2] = *(const short8*)&Abuf[4096 + au];
            }
#pragma unroll
            for (int pt = 0; pt < NPT; ++pt) {
                const int boff = (pt * 16 + mrow) * KS + kq * 8;
                const short8 bh = *(const short8*)&Shi[boff];
                const short8 bl = *(const short8*)&Slo[boff];
#pragma unroll
                for (int mt2 = 0; mt2 < MTW; ++mt2) {
                    f32x4 a = acc[mt2 * NPT + pt];
                    a = __builtin_amdgcn_mfma_f32_16x16x32_bf16(alv[mt2], bh, a, 0, 0, 0);
                    a = __builtin_amdgcn_mfma_f32_16x16x32_bf16(ahv[mt2], bl, a, 0, 0, 0);
                    a = __builtin_amdgcn_mfma_f32_16x16x32_bf16(ahv[mt2], bh, a, 0, 0, 0);
                    acc[mt2 * NPT + pt] = a;
                }
            }
            __builtin_amdgcn_s_setprio(0);
            if (ch + 1 < NCH) {
                asm volatile("s_waitcnt lgkmcnt(0)" ::: "memory");
                __builtin_amdgcn_s_barrier();
                __builtin_amdgcn_sched_barrier(0);
                // ---- write phase: ds_write A(ch+1) from regs (loads landed),
                //      finish gathers -> S, issue next gathers + next A ----
                {
                    const int u0 = tid, u1 = tid + NT;
                    const int u2 = tid + 2 * NT, u3 = tid + 3 * NT;
                    *(short8*)&Abuf[(size_t)u0 * 8] = ar0;
                    *(short8*)&Abuf[(size_t)u1 * 8] = ar1;
                    *(short8*)&Abuf[(size_t)u2 * 8] = ar2;
                    *(short8*)&Abuf[(size_t)u3 * 8] = ar3;
                }
                sample_finish<CIN, HH, WW, POS, KS>(ewt, v0, v1, Shi, Slo,
                                                    tt, (ch + 1) * KC);
                if (ch + 2 < NCH) {
                    sample_issue<CIN, HH, WW, POS>(xb, eoff2, v0, v1, tt,
                                                   (ch + 2) * KC);
                    const size_t wb = (size_t)(ch + 2) * 4096;
                    const int u0 = tid, u1 = tid + NT;
                    const int u2 = tid + 2 * NT, u3 = tid + 3 * NT;
                    ar0 = *(const short8*)((u0 < 512 ? whi + wb + (size_t)u0 * 8
                                                     : wlo + wb + (size_t)(u0 - 512) * 8));
                    ar1 = *(const short8*)((u1 < 512 ? whi + wb + (size_t)u1 * 8
                                                     : wlo + wb + (size_t)(u1 - 512) * 8));
                    ar2 = *(const short8*)((u2 < 512 ? whi + wb + (size_t)u2 * 8
                                                     : wlo + wb + (size_t)(u2 - 512) * 8));
                    ar3 = *(const short8*)((u3 < 512 ? whi + wb + (size_t)u3 * 8
                                                     : wlo + wb + (size_t)(u3 - 512) * 8));
                }
                asm volatile("s_waitcnt lgkmcnt(0)" ::: "memory");
                __builtin_amdgcn_s_barrier();
                __builtin_amdgcn_sched_barrier(0);
            }
        }
    } else {
        ushort* S00 = Sbase + kgid * (4 * SBUF);
        sample_chunk<CIN, HH, WW, POS, KS>(xb, eoff2, ewt, S00, S00 + SBUF,
                                           tt, kgid * NCH * KC);
        __syncthreads();

        for (int ch = 0; ch < NCH; ++ch) {
            const int cur = ch & 1;
            ushort* Sc = S00 + (cur * 2) * SBUF;
            // B fragments for all pos-tiles (held across the sampler)
            short8 bhv[NPT], blv[NPT];
#pragma unroll
            for (int pt = 0; pt < NPT; ++pt) {
                const int boff = (pt * 16 + mrow) * KS + kq * 8;
                bhv[pt] = *(const short8*)&Sc[boff];
                blv[pt] = *(const short8*)&Sc[SBUF + boff];
            }
            if (ch + 1 < NCH) {
                ushort* Sn = S00 + ((cur ^ 1) * 2) * SBUF;
                sample_chunk<CIN, HH, WW, POS, KS>(xb, eoff2, ewt,
                                                   Sn, Sn + SBUF, tt,
                                                   (kgid * NCH + ch + 1) * KC);
            }
            // A fragments just-in-time from global (fragment order, coalesced)
            const size_t abase = (size_t)((kgid * NCH + ch) * 8) * 512;
            __builtin_amdgcn_s_setprio(1);
#pragma unroll
            for (int mt2 = 0; mt2 < MTW; ++mt2) {
                const size_t ao = abase + (size_t)(((m0 + mt2) * 64 + lane) * 8);
                const short8 ah = *(const short8*)(whi + ao);
                const short8 al = *(const short8*)(wlo + ao);
#pragma unroll
                for (int pt = 0; pt < NPT; ++pt) {
                    f32x4 a = acc[mt2 * NPT + pt];
                    a = __builtin_amdgcn_mfma_f32_16x16x32_bf16(al, bhv[pt], a, 0, 0, 0);
                    a = __builtin_amdgcn_mfma_f32_16x16x32_bf16(ah, blv[pt], a, 0, 0, 0);
                    a = __builtin_amdgcn_mfma_f32_16x16x32_bf16(ah, bhv[pt], a, 0, 0, 0);
                    acc[mt2 * NPT + pt] = a;
                }
            }
            __builtin_amdgcn_s_setprio(0);
            __syncthreads();
        }
    }

    constexpr int RS = POS + 1;
    constexpr int SL = 128 * RS;
    float* red = (float*)Sbase;

    if constexpr (KWAVES == 4) {
        if (kgid >= 2) {
#pragma unroll
            for (int mt2 = 0; mt2 < MTW; ++mt2)
#pragma unroll
                for (int pt = 0; pt < NPT; ++pt)
#pragma unroll
                    for (int r = 0; r < 4; ++r) {
                        const int co = (m0 + mt2) * 16 + kq * 4 + r;
                        red[(kgid - 2) * SL + co * RS + pt * 16 + mrow] =
                            acc[mt2 * NPT + pt][r];
                    }
        }
        __syncthreads();
        if (kgid < 2) {
#pragma unroll
            for (int mt2 = 0; mt2 < MTW; ++mt2)
#pragma unroll
                for (int pt = 0; pt < NPT; ++pt)
#pragma unroll
                    for (int r = 0; r < 4; ++r) {
                        const int co = (m0 + mt2) * 16 + kq * 4 + r;
                        acc[mt2 * NPT + pt][r] +=
                            red[kgid * SL + co * RS + pt * 16 + mrow];
                    }
        }
        __syncthreads();
        if (kgid == 1) {
#pragma unroll
            for (int mt2 = 0; mt2 < MTW; ++mt2)
#pragma unroll
                for (int pt = 0; pt < NPT; ++pt)
#pragma unroll
                    for (int r = 0; r < 4; ++r) {
                        const int co = (m0 + mt2) * 16 + kq * 4 + r;
                        red[co * RS + pt * 16 + mrow] = acc[mt2 * NPT + pt][r];
                    }
        }
        __syncthreads();
        if (kgid == 0) {
#pragma unroll
            for (int mt2 = 0; mt2 < MTW; ++mt2)
#pragma unroll
                for (int pt = 0; pt < NPT; ++pt)
#pragma unroll
                    for (int r = 0; r < 4; ++r) {
                        const int co = (m0 + mt2) * 16 + kq * 4 + r;
                        acc[mt2 * NPT + pt][r] += red[co * RS + pt * 16 + mrow];
                    }
        }
    } else if constexpr (KWAVES == 2) {
        if (kgid == 1) {
#pragma unroll
            for (int mt2 = 0; mt2 < MTW; ++mt2)
#pragma unroll
                for (int pt = 0; pt < NPT; ++pt)
#pragma unroll
                    for (int r = 0; r < 4; ++r) {
                        const int co = (m0 + mt2) * 16 + kq * 4 + r;
                        red[co * RS + pt * 16 + mrow] = acc[mt2 * NPT + pt][r];
                    }
        }
        __syncthreads();
        if (kgid == 0) {
#pragma unroll
            for (int mt2 = 0; mt2 < MTW; ++mt2)
#pragma unroll
                for (int pt = 0; pt < NPT; ++pt)
#pragma unroll
                    for (int r = 0; r < 4; ++r) {
                        const int co = (m0 + mt2) * 16 + kq * 4 + r;
                        acc[mt2 * NPT + pt][r] += red[co * RS + pt * 16 + mrow];
                    }
        }
    }

    if (kgid == 0) {
        float* outb = out + (size_t)b * 128 * HW + p0;
#pragma unroll
        for (int mt2 = 0; mt2 < MTW; ++mt2)
#pragma unroll
            for (int pt = 0; pt < NPT; ++pt)
#pragma unroll
                for (int r = 0; r < 4; ++r) {
                    const int co = (m0 + mt2) * 16 + kq * 4 + r;
                    outb[(size_t)co * HW + pt * 16 + mrow] =
                        fmaxf(acc[mt2 * NPT + pt][r] * invp[co] + shp[co], 0.f);
                }
    }
}

// ---------------- depthwise transposed-conv upsample x2 (k=4, pad 2) --------
// R21: 4 consecutive ox outputs per thread. ox0 % 4 == 0 => tap parity is
// the compile-time dx parity: all kx skip-branches constant-fold, no wave
// divergence. float4 coalesced store. Per-output tap order unchanged.
__global__ __launch_bounds__(256) void upsample_kernel(
    const float* __restrict__ y,    // (4,128,64,64)
    const float* __restrict__ wup,  // (128,1,4,4)
    float* __restrict__ out)        // (4,128,128,128)
{
    const int t   = blockIdx.x * 256 + threadIdx.x;   // 2097152 total
    const int ox0 = (t & 31) * 4;
    const int oy  = (t >> 5) & 127;
    const int c   = (t >> 12) & 127;
    const int b   = t >> 19;

    const float* yc = y + (size_t)(b * 128 + c) * 4096;
    const float* wc = wup + c * 16;

    float r[4];
#pragma unroll
    for (int dx = 0; dx < 4; ++dx) {
        const int ox = ox0 + dx;
        float acc = 0.f;
#pragma unroll
        for (int ky = 0; ky < 4; ++ky) {
            const int qy = oy + ky - 2;
            if (qy & 1) continue;               // half-wave-uniform (oy)
            const int iy = qy >> 1;
            if (iy < 0 || iy >= 64) continue;
#pragma unroll
            for (int kx = 0; kx < 4; ++kx) {
                const int qx = ox + kx - 2;
                if ((dx + kx) & 1) continue;    // compile-time parity
                const int ix = qx >> 1;
                if (ix < 0 || ix >= 64) continue;
                acc += yc[iy * 64 + ix] * wc[(3 - ky) * 4 + (3 - kx)];
            }
        }
        r[dx] = acc;
    }
    float4 v; v.x = r[0]; v.y = r[1]; v.z = r[2]; v.w = r[3];
    *reinterpret_cast<float4*>(&out[(size_t)t * 4]) = v;
}

// ---------------------------------------------------------------------------
extern "C" void kernel_launch(void* const* d_in, const int* in_sizes, int n_in,
                              void* d_out, int out_size, void* d_ws, size_t ws_size,
                              hipStream_t stream) {
    const float* x      = (const float*)d_in[0];
    const float* w_off1 = (const float*)d_in[1];
    const float* b_off1 = (const float*)d_in[2];
    const float* w1     = (const float*)d_in[3];
    const float* b1     = (const float*)d_in[4];
    const float* g1v    = (const float*)d_in[5];
    const float* be1    = (const float*)d_in[6];
    const float* m1     = (const float*)d_in[7];
    const float* v1     = (const float*)d_in[8];
    const float* w_up   = (const float*)d_in[9];
    const float* w_off2 = (const float*)d_in[10];
    const float* b_off2 = (const float*)d_in[11];
    const float* w2     = (const float*)d_in[12];
    const float* b2     = (const float*)d_in[13];
    const float* g2v    = (const float*)d_in[14];
    const float* be2    = (const float*)d_in[15];
    const float* m2     = (const float*)d_in[16];
    const float* v2     = (const float*)d_in[17];

    float* ws  = (float*)d_ws;
    float* om1 = ws;                     // 4*27*4096   =   442368 f
    float* y1  = om1 + 442368;           // 4*128*4096  =  2097152 f
    float* up  = y1 + 2097152;           // 4*128*16384 =  8388608 f
    float* om2 = up + 8388608;           // 4*27*16384  =  1769472 f
    float* outf = (float*)d_out;

    // `up` region (dead until upsample writes it): w1 + w_off1 splits
    ushort* w1hi  = (ushort*)up;         // 294912
    ushort* w1lo  = w1hi + 294912;       // 294912
    ushort* wo1hi = w1lo + 294912;       // 32*2304 = 73728
    ushort* wo1lo = wo1hi + 73728;       // 73728
    // `y1` region (dead after upsample reads it): w2 + w_off2 splits
    ushort* w2hi  = (ushort*)y1;         // 147456
    ushort* w2lo  = w2hi + 147456;       // 147456
    ushort* wo2hi = w2lo + 147456;       // 32*1152 = 36864
    ushort* wo2lo = wo2hi + 36864;       // 36864

    // prep: w1 (dcn1) + w_off1 (conv1) splits, fragment order
    wsplit_perm_kernel<<<(294912 + 255) / 256, 256, 0, stream>>>(
        w1, w1hi, w1lo, 256, 294912);
    wsplit_perm_conv_kernel<<<(73728 + 255) / 256, 256, 0, stream>>>(
        w_off1, wo1hi, wo1lo, 256, 73728);

    // om1 = conv3x3(x, w_off1) + b_off1 — MFMA, POS=16, KWAVES=4
    conv_mfma_kernel<256, 64, 64, 16, 4, 4>
        <<<1024, 256, 21632, stream>>>(x, wo1hi, wo1lo, b_off1, om1);

    // y1 = bn_relu(dcn1) — MFMA, POS=32, 4-way K-split, M-split waves
    dcn_mfma_kernel<256, 64, 64, 32, 4, 4, false, false>
        <<<4 * (4096 / 32), 512, 47744, stream>>>(
        x, om1, om1, w1hi, w1lo, b1, g1v, be1, m1, v1, y1);
    // up = depthwise transposed upsample — 4 outputs/thread, float4 stores
    upsample_kernel<<<2097152 / 256, 256, 0, stream>>>(y1, w_up, up);

    // prep: w2 (dcn2) + w_off2 (conv2) splits (y1 now dead)
    wsplit_perm_kernel<<<(147456 + 255) / 256, 256, 0, stream>>>(
        w2, w2hi, w2lo, 128, 147456);
    wsplit_perm_conv_kernel<<<(36864 + 255) / 256, 256, 0, stream>>>(
        w_off2, wo2hi, wo2lo, 128, 36864);

    // om2 = conv3x3(up, w_off2) + b_off2 — MFMA, POS=64, KWAVES=1
    conv_mfma_kernel<128, 128, 128, 64, 1, 4>
        <<<1024, 256, 25088, stream>>>(up, wo2hi, wo2lo, b_off2, om2);

    // out = bn_relu(dcn2) — MFMA, POS=64, A-staged (split), single-S, M-split
    dcn_mfma_kernel<128, 128, 128, 64, 1, 4, true, false>
        <<<4 * (16384 / 64), 256, 39168, stream>>>(
        up, om2, om2, w2hi, w2lo, b2, g2v, be2, m2, v2, outf);
}